// Round 2
// baseline (10915.635 us; speedup 1.0000x reference)
//
#include <hip/hip_runtime.h>
#include <hip/hip_bf16.h>
#include <cstdint>
#include <cstddef>

#define NN 30000
#define EE 150000

using u16 = unsigned short;
using u32 = unsigned int;

__device__ __forceinline__ float bl2f(u16 u) { return __uint_as_float(((u32)u) << 16); }
__device__ __forceinline__ u16 f2bl(float f) {
    u32 x = __float_as_uint(f);
    return (u16)((x + 0x7fffu + ((x >> 16) & 1u)) >> 16);
}

// ---------------- CSR build ----------------
__global__ void k_count(const int* __restrict__ dst, int* __restrict__ cnt) {
    int e = blockIdx.x * 256 + threadIdx.x;
    if (e < EE) atomicAdd(&cnt[dst[e]], 1);
}

__global__ void k_scan(const int* __restrict__ cnt, int* __restrict__ offs) {
    __shared__ int ss[1024];
    int t = threadIdx.x;
    int base = t * 30;
    int s = 0;
    for (int i = 0; i < 30; i++) { int idx = base + i; if (idx < NN) s += cnt[idx]; }
    ss[t] = s; __syncthreads();
    for (int off = 1; off < 1024; off <<= 1) {
        int v = (t >= off) ? ss[t - off] : 0;
        __syncthreads();
        ss[t] += v;
        __syncthreads();
    }
    int run = (t == 0) ? 0 : ss[t - 1];
    for (int i = 0; i < 30; i++) {
        int idx = base + i;
        if (idx < NN) { offs[idx] = run; run += cnt[idx]; }
    }
    if (t == 1023) offs[NN] = run;
}

__global__ void k_scatter(const int* __restrict__ src, const int* __restrict__ dst,
                          const int* __restrict__ offs, int* __restrict__ fill,
                          int* __restrict__ csr) {
    int e = blockIdx.x * 256 + threadIdx.x;
    if (e < EE) {
        int d = dst[e];
        int p = offs[d] + atomicAdd(&fill[d], 1);
        csr[p] = src[e];
    }
}

// ---------------- pre linear: h[c][n] = x @ pre_w + pre_b ----------------
__global__ void k_pre(const float* __restrict__ x, const float* __restrict__ pw,
                      const float* __restrict__ pb, float* __restrict__ h) {
    int n = blockIdx.x * 256 + threadIdx.x;
    if (n >= NN) return;
    float x0 = x[2 * n], x1 = x[2 * n + 1];
    for (int c = 0; c < 75; c++) {
        float v = fmaf(x0, pw[c], fmaf(x1, pw[75 + c], pb[c]));
        h[(size_t)c * NN + n] = v;
    }
}

// ---------------- per-node base: base[v][o] = bp[o] + sum_f h[v][f]*Wp[t][f][c] (f<75) ----
__global__ __launch_bounds__(384) void k_base(const float* __restrict__ h,
                                              const float* __restrict__ Wp,
                                              const float* __restrict__ bp,
                                              u16* __restrict__ baseb) {
    __shared__ __align__(16) u16 wpA[30000];   // 10 chunks x 375 lanes x 8 (bf16)
    __shared__ __align__(16) float hv[80];
    __shared__ float bps[384];
    for (int idx = threadIdx.x; idx < 30000; idx += 384) {
        int c = idx % 75;
        int fh = (idx / 75) % 80;
        int t = idx / 6000;
        int o = t * 75 + c;
        u16 v = 0;
        if (fh < 75) v = f2bl(Wp[(t * 150 + fh) * 75 + c]);
        wpA[(fh >> 3) * 3000 + o * 8 + (fh & 7)] = v;
    }
    if (threadIdx.x < 375) bps[threadIdx.x] = bp[threadIdx.x];
    int o = threadIdx.x;
    bool act = o < 375;
    for (int v = blockIdx.x; v < NN; v += gridDim.x) {
        __syncthreads();
        if (threadIdx.x < 80) hv[threadIdx.x] = (threadIdx.x < 75) ? h[(size_t)threadIdx.x * NN + v] : 0.f;
        __syncthreads();
        if (act) {
            float acc = bps[o];
#pragma unroll
            for (int cc = 0; cc < 10; cc++) {
                uint4 w = *reinterpret_cast<const uint4*>(&wpA[cc * 3000 + o * 8]);
                float4 uA = *reinterpret_cast<const float4*>(&hv[cc * 8]);
                float4 uB = *reinterpret_cast<const float4*>(&hv[cc * 8 + 4]);
                float lo, hi;
                lo = __uint_as_float(w.x << 16); hi = __uint_as_float(w.x & 0xffff0000u);
                acc = fmaf(lo, uA.x, acc); acc = fmaf(hi, uA.y, acc);
                lo = __uint_as_float(w.y << 16); hi = __uint_as_float(w.y & 0xffff0000u);
                acc = fmaf(lo, uA.z, acc); acc = fmaf(hi, uA.w, acc);
                lo = __uint_as_float(w.z << 16); hi = __uint_as_float(w.z & 0xffff0000u);
                acc = fmaf(lo, uB.x, acc); acc = fmaf(hi, uB.y, acc);
                lo = __uint_as_float(w.w << 16); hi = __uint_as_float(w.w & 0xffff0000u);
                acc = fmaf(lo, uB.z, acc); acc = fmaf(hi, uB.w, acc);
            }
            baseb[(size_t)v * 376 + o] = f2bl(acc);
        }
    }
}

// ---------------- per-node edge aggregation ----------------
#define EDGE_FMA(J, ACC) { \
    float4 p = *reinterpret_cast<const float4*>(&hu[J][cc * 8]); \
    float4 q = *reinterpret_cast<const float4*>(&hu[J][cc * 8 + 4]); \
    ACC = fmaf(w0, p.x, ACC); ACC = fmaf(w1, p.y, ACC); ACC = fmaf(w2, p.z, ACC); ACC = fmaf(w3, p.w, ACC); \
    ACC = fmaf(w4, q.x, ACC); ACC = fmaf(w5, q.y, ACC); ACC = fmaf(w6, q.z, ACC); ACC = fmaf(w7, q.w, ACC); }

#define STAT_UPD(A) { sum += A; sq += A * A; mn = fminf(mn, A); mx = fmaxf(mx, A); }

__global__ __launch_bounds__(384) void k_edge(const float* __restrict__ h,
                                              const int* __restrict__ offs,
                                              const int* __restrict__ csr,
                                              const float* __restrict__ Wp,
                                              const u16* __restrict__ baseb,
                                              u16* __restrict__ agg) {
    __shared__ __align__(16) u16 wpB[30000];
    __shared__ __align__(16) float hu[4][80];
    __shared__ int su[4];
    for (int idx = threadIdx.x; idx < 30000; idx += 384) {
        int c = idx % 75;
        int fh = (idx / 75) % 80;
        int t = idx / 6000;
        int o = t * 75 + c;
        u16 v = 0;
        if (fh < 75) v = f2bl(Wp[(t * 150 + 75 + fh) * 75 + c]);
        wpB[(fh >> 3) * 3000 + o * 8 + (fh & 7)] = v;
    }
    int o = threadIdx.x;
    bool act = o < 375;
    for (int v = blockIdx.x; v < NN; v += gridDim.x) {
        int e0 = offs[v], e1 = offs[v + 1];
        float base = 0.f;
        if (act) base = bl2f(baseb[(size_t)v * 376 + o]);
        float sum = 0.f, sq = 0.f, mn = 3.4e38f, mx = -3.4e38f;
        for (int e = e0; e < e1; e += 4) {
            int g = e1 - e; if (g > 4) g = 4;
            __syncthreads();
            if (threadIdx.x < 4) {
                int idx = e + (threadIdx.x < g ? threadIdx.x : g - 1);
                su[threadIdx.x] = csr[idx];
            }
            __syncthreads();
            if (threadIdx.x < 320) {
                int j = threadIdx.x / 80, f = threadIdx.x % 80;
                hu[j][f] = (f < 75) ? h[(size_t)f * NN + su[j]] : 0.f;
            }
            __syncthreads();
            if (act) {
                float a0 = base, a1 = base, a2 = base, a3 = base;
#pragma unroll
                for (int cc = 0; cc < 10; cc++) {
                    uint4 w = *reinterpret_cast<const uint4*>(&wpB[cc * 3000 + o * 8]);
                    float w0 = __uint_as_float(w.x << 16), w1 = __uint_as_float(w.x & 0xffff0000u);
                    float w2 = __uint_as_float(w.y << 16), w3 = __uint_as_float(w.y & 0xffff0000u);
                    float w4 = __uint_as_float(w.z << 16), w5 = __uint_as_float(w.z & 0xffff0000u);
                    float w6 = __uint_as_float(w.w << 16), w7 = __uint_as_float(w.w & 0xffff0000u);
                    EDGE_FMA(0, a0)
                    EDGE_FMA(1, a1)
                    EDGE_FMA(2, a2)
                    EDGE_FMA(3, a3)
                }
                STAT_UPD(a0)
                if (g > 1) STAT_UPD(a1)
                if (g > 2) STAT_UPD(a2)
                if (g > 3) STAT_UPD(a3)
            }
        }
        if (act) {
            int deg = e1 - e0;
            float cf = (float)(deg > 0 ? deg : 1);
            float mean = sum / cf, mean2 = sq / cf;
            float var = mean2 - mean * mean; if (var < 0.f) var = 0.f;
            float sd = sqrtf(var + 1e-5f);
            float mnv = deg > 0 ? mn : 0.f;
            float mxv = deg > 0 ? mx : 0.f;
            int t = o / 75, c = o % 75;
            size_t b = (size_t)v * 1520 + t * 304 + c;
            agg[b] = f2bl(mean);
            agg[b + 75] = f2bl(mnv);
            agg[b + 150] = f2bl(mxv);
            agg[b + 225] = f2bl(sd);
        }
    }
}

// ---------------- post tower MLP: tmp[tj][n] ----------------
__global__ void k_post(const float* __restrict__ h, const int* __restrict__ offs,
                       const u16* __restrict__ agg, const float* __restrict__ Wq,
                       const float* __restrict__ bq, const float* __restrict__ adl_p,
                       float* __restrict__ tmp) {
    int tj = blockIdx.x;            // 0..74
    int t = tj / 15, j = tj % 15;
    int n = blockIdx.y * 256 + threadIdx.x;
    if (n >= NN) return;
    float adl = adl_p[0];
    int deg = offs[n + 1] - offs[n];
    float dc = (float)(deg > 0 ? deg : 1);
    float amp = log1pf(dc) / adl;
    float inv = 1.f / amp;
    const float* wc = Wq + (size_t)t * 975 * 15 + j;
    float acc = bq[t * 15 + j];
    for (int c = 0; c < 75; c++)
        acc = fmaf(h[(size_t)c * NN + n], wc[c * 15], acc);
    const u16* ar = agg + (size_t)n * 1520 + t * 304;
    float s1 = 0.f, s2 = 0.f, s3 = 0.f;
    for (int g = 0; g < 296; g += 8) {
        uint4 av = *reinterpret_cast<const uint4*>(&ar[g]);
        float af[8];
        af[0] = __uint_as_float(av.x << 16); af[1] = __uint_as_float(av.x & 0xffff0000u);
        af[2] = __uint_as_float(av.y << 16); af[3] = __uint_as_float(av.y & 0xffff0000u);
        af[4] = __uint_as_float(av.z << 16); af[5] = __uint_as_float(av.z & 0xffff0000u);
        af[6] = __uint_as_float(av.w << 16); af[7] = __uint_as_float(av.w & 0xffff0000u);
        const float* wA = wc + (75 + g) * 15;
        const float* wB = wc + (375 + g) * 15;
        const float* wC = wc + (675 + g) * 15;
#pragma unroll
        for (int k = 0; k < 8; k++) {
            s1 = fmaf(af[k], wA[k * 15], s1);
            s2 = fmaf(af[k], wB[k * 15], s2);
            s3 = fmaf(af[k], wC[k * 15], s3);
        }
    }
    for (int g = 296; g < 300; g++) {
        float a = bl2f(ar[g]);
        s1 = fmaf(a, wc[(75 + g) * 15], s1);
        s2 = fmaf(a, wc[(375 + g) * 15], s2);
        s3 = fmaf(a, wc[(675 + g) * 15], s3);
    }
    acc += s1 + amp * s2 + inv * s3;
    tmp[(size_t)tj * NN + n] = acc;
}

// ---------------- W_lin + BN stats ----------------
__global__ void k_lin(const float* __restrict__ tmp, const float* __restrict__ Wl,
                      const float* __restrict__ bl, float* __restrict__ h,
                      float* __restrict__ bsum, float* __restrict__ bsq) {
    int c = blockIdx.x;
    int n = blockIdx.y * 256 + threadIdx.x;
    int nc = n < NN ? n : NN - 1;
    float acc = bl[c];
    for (int k = 0; k < 75; k++)
        acc = fmaf(tmp[(size_t)k * NN + nc], Wl[k * 75 + c], acc);
    bool valid = n < NN;
    if (valid) h[(size_t)c * NN + n] = acc;
    __shared__ float s1[256], s2[256];
    s1[threadIdx.x] = valid ? acc : 0.f;
    s2[threadIdx.x] = valid ? acc * acc : 0.f;
    __syncthreads();
    for (int w = 128; w > 0; w >>= 1) {
        if (threadIdx.x < w) {
            s1[threadIdx.x] += s1[threadIdx.x + w];
            s2[threadIdx.x] += s2[threadIdx.x + w];
        }
        __syncthreads();
    }
    if (threadIdx.x == 0) {
        atomicAdd(&bsum[c], s1[0]);
        atomicAdd(&bsq[c], s2[0]);
    }
}

__global__ void k_bn(float* __restrict__ h, const float* __restrict__ bsum,
                     const float* __restrict__ bsq, const float* __restrict__ g,
                     const float* __restrict__ b) {
    int c = blockIdx.x;
    int n = blockIdx.y * 256 + threadIdx.x;
    if (n >= NN) return;
    float mu = bsum[c] * (1.f / NN);
    float var = bsq[c] * (1.f / NN) - mu * mu;
    float sc = g[c] * rsqrtf(var + 1e-5f);
    float v = h[(size_t)c * NN + n];
    v = (v - mu) * sc + b[c];
    h[(size_t)c * NN + n] = v > 0.f ? v : 0.f;
}

// ---------------- MLP head ----------------
__global__ void k_mlp1(const float* __restrict__ h, const float* __restrict__ alpha,
                       const int* __restrict__ batch, const float* __restrict__ w1,
                       const float* __restrict__ b1, float* __restrict__ t1) {
    int j = blockIdx.x;             // 0..49
    int n = blockIdx.y * 256 + threadIdx.x;
    if (n >= NN) return;
    float acc = b1[j];
    for (int c = 0; c < 75; c++)
        acc = fmaf(h[(size_t)c * NN + n], w1[c * 50 + j], acc);
    float a = alpha[batch[n]];
    acc = fmaf(a, w1[75 * 50 + j], acc);
    t1[(size_t)j * NN + n] = acc > 0.f ? acc : 0.f;
}

__global__ void k_mlp2(const float* __restrict__ t1, const float* __restrict__ w2,
                       const float* __restrict__ b2, const float* __restrict__ w3,
                       const float* __restrict__ b3, const float* __restrict__ noise,
                       const float* __restrict__ x, float* __restrict__ out) {
    int n = blockIdx.x * 256 + threadIdx.x;
    if (n >= NN) return;
    float tr[50];
#pragma unroll
    for (int k = 0; k < 50; k++) tr[k] = t1[(size_t)k * NN + n];
    float y = b3[0];
#pragma unroll
    for (int k2 = 0; k2 < 25; k2++) {
        float acc = b2[k2];
#pragma unroll
        for (int k = 0; k < 50; k++) acc = fmaf(tr[k], w2[k * 25 + k2], acc);
        acc = acc > 0.f ? acc : 0.f;
        y = fmaf(acc, w3[k2], y);
    }
    float z = y + noise[n];
    float s = 1.f / (1.f + expf(-z));
    out[n] = s;
    out[NN + n] = x[2 * n];   // fixed_feature passthrough (exact)
}

extern "C" void kernel_launch(void* const* d_in, const int* in_sizes, int n_in,
                              void* d_out, int out_size, void* d_ws, size_t ws_size,
                              hipStream_t stream) {
    const float* x      = (const float*)d_in[0];
    const float* alpha  = (const float*)d_in[1];
    const int*   ei     = (const int*)d_in[2];
    const int*   batch  = (const int*)d_in[3];
    const float* noise  = (const float*)d_in[4];
    const float* adl    = (const float*)d_in[5];
    const float* pre_w  = (const float*)d_in[6];
    const float* pre_b  = (const float*)d_in[7];
    const float* W_pre  = (const float*)d_in[8];
    const float* b_pre  = (const float*)d_in[9];
    const float* W_post = (const float*)d_in[10];
    const float* b_post = (const float*)d_in[11];
    const float* W_lin  = (const float*)d_in[12];
    const float* b_lin  = (const float*)d_in[13];
    const float* bn_g   = (const float*)d_in[14];
    const float* bn_b   = (const float*)d_in[15];
    const float* mw1    = (const float*)d_in[16];
    const float* mb1    = (const float*)d_in[17];
    const float* mw2    = (const float*)d_in[18];
    const float* mb2    = (const float*)d_in[19];
    const float* mw3    = (const float*)d_in[20];
    const float* mb3    = (const float*)d_in[21];
    (void)in_sizes; (void)n_in; (void)out_size; (void)ws_size;

    char* ws = (char*)d_ws;
    size_t off = 0;
    auto alloc = [&](size_t bytes) -> char* {
        char* p = ws + off;
        off += (bytes + 255) & ~((size_t)255);
        return p;
    };
    float* h     = (float*)alloc((size_t)75 * NN * 4);       // [75][N]
    float* tmp   = (float*)alloc((size_t)75 * NN * 4);       // [75][N], reused as t1
    u16*   agg   = (u16*)alloc((size_t)NN * 1520 * 2);       // [N][5][304] bf16
    u16*   baseb = (u16*)alloc((size_t)NN * 376 * 2);        // [N][376] bf16
    int*   cnt   = (int*)alloc((size_t)NN * 4);
    int*   offs  = (int*)alloc((size_t)(NN + 1) * 4);
    int*   fill  = (int*)alloc((size_t)NN * 4);
    int*   csr   = (int*)alloc((size_t)EE * 4);
    float* bnsum = (float*)alloc(4 * 75 * 4);
    float* bnsq  = (float*)alloc(4 * 75 * 4);

    hipMemsetAsync(cnt, 0, (size_t)NN * 4, stream);
    hipMemsetAsync(fill, 0, (size_t)NN * 4, stream);
    hipMemsetAsync(bnsum, 0, 4 * 75 * 4, stream);
    hipMemsetAsync(bnsq, 0, 4 * 75 * 4, stream);

    const int* src = ei;
    const int* dst = ei + EE;
    int eb = (EE + 255) / 256;
    int nb = (NN + 255) / 256;

    k_count<<<eb, 256, 0, stream>>>(dst, cnt);
    k_scan<<<1, 1024, 0, stream>>>(cnt, offs);
    k_scatter<<<eb, 256, 0, stream>>>(src, dst, offs, fill, csr);
    k_pre<<<nb, 256, 0, stream>>>(x, pre_w, pre_b, h);

    for (int l = 0; l < 4; l++) {
        const float* Wp  = W_pre + (size_t)l * 5 * 150 * 75;
        const float* bp  = b_pre + l * 375;
        const float* Wq  = W_post + (size_t)l * 5 * 975 * 15;
        const float* bq  = b_post + l * 75;
        const float* Wl  = W_lin + l * 75 * 75;
        const float* blp = b_lin + l * 75;
        k_base<<<1024, 384, 0, stream>>>(h, Wp, bp, baseb);
        k_edge<<<1024, 384, 0, stream>>>(h, offs, csr, Wp, baseb, agg);
        k_post<<<dim3(75, nb), 256, 0, stream>>>(h, offs, agg, Wq, bq, adl, tmp);
        k_lin<<<dim3(75, nb), 256, 0, stream>>>(tmp, Wl, blp, h, bnsum + l * 75, bnsq + l * 75);
        k_bn<<<dim3(75, nb), 256, 0, stream>>>(h, bnsum + l * 75, bnsq + l * 75,
                                               bn_g + l * 75, bn_b + l * 75);
    }

    float* t1 = tmp;
    k_mlp1<<<dim3(50, nb), 256, 0, stream>>>(h, alpha, batch, mw1, mb1, t1);
    k_mlp2<<<nb, 256, 0, stream>>>(t1, mw2, mb2, mw3, mb3, noise, x, (float*)d_out);
}

// Round 3
// 9275.934 us; speedup vs baseline: 1.1768x; 1.1768x over previous
//
#include <hip/hip_runtime.h>
#include <hip/hip_bf16.h>
#include <cstdint>
#include <cstddef>

#define NN 30000
#define EE 150000

using u16 = unsigned short;
using u32 = unsigned int;

__device__ __forceinline__ float bl2f(u16 u) { return __uint_as_float(((u32)u) << 16); }
__device__ __forceinline__ u16 f2bl(float f) {
    u32 x = __float_as_uint(f);
    return (u16)((x + 0x7fffu + ((x >> 16) & 1u)) >> 16);
}
__device__ __forceinline__ u32 pack2(float a, float b) {
    return (u32)f2bl(a) | ((u32)f2bl(b) << 16);
}

// ---------------- CSR build ----------------
__global__ void k_count(const int* __restrict__ dst, int* __restrict__ cnt) {
    int e = blockIdx.x * 256 + threadIdx.x;
    if (e < EE) atomicAdd(&cnt[dst[e]], 1);
}

__global__ void k_scan(const int* __restrict__ cnt, int* __restrict__ offs) {
    __shared__ int ss[1024];
    int t = threadIdx.x;
    int base = t * 30;
    int s = 0;
    for (int i = 0; i < 30; i++) { int idx = base + i; if (idx < NN) s += cnt[idx]; }
    ss[t] = s; __syncthreads();
    for (int off = 1; off < 1024; off <<= 1) {
        int v = (t >= off) ? ss[t - off] : 0;
        __syncthreads();
        ss[t] += v;
        __syncthreads();
    }
    int run = (t == 0) ? 0 : ss[t - 1];
    for (int i = 0; i < 30; i++) {
        int idx = base + i;
        if (idx < NN) { offs[idx] = run; run += cnt[idx]; }
    }
    if (t == 1023) offs[NN] = run;
}

__global__ void k_scatter(const int* __restrict__ src, const int* __restrict__ dst,
                          const int* __restrict__ offs, int* __restrict__ fill,
                          int* __restrict__ csr) {
    int e = blockIdx.x * 256 + threadIdx.x;
    if (e < EE) {
        int d = dst[e];
        int p = offs[d] + atomicAdd(&fill[d], 1);
        csr[p] = src[e];
    }
}

// ---------------- pre linear: hN[n][80] = x @ pre_w + pre_b (pad zeros) ----------------
__global__ void k_pre(const float* __restrict__ x, const float* __restrict__ pw,
                      const float* __restrict__ pb, float* __restrict__ hN) {
    int n = blockIdx.x * 256 + threadIdx.x;
    if (n >= NN) return;
    float x0 = x[2 * n], x1 = x[2 * n + 1];
    float buf[80];
#pragma unroll
    for (int c = 0; c < 80; c++)
        buf[c] = (c < 75) ? fmaf(x0, pw[c], fmaf(x1, pw[75 + c], pb[c])) : 0.f;
    float4* dstp = (float4*)(hN + (size_t)n * 80);
#pragma unroll
    for (int w = 0; w < 20; w++)
        dstp[w] = make_float4(buf[4 * w], buf[4 * w + 1], buf[4 * w + 2], buf[4 * w + 3]);
}

// ---------------- k_base: baseb[v][o] f32, 4 nodes per pass ----------------
__global__ __launch_bounds__(384) void k_base(const float* __restrict__ hN,
                                              const float* __restrict__ Wp,
                                              const float* __restrict__ bp,
                                              float* __restrict__ baseb) {
    __shared__ __align__(16) u16 wpA[30000];   // 10 chunks x 375 lanes x 8 (bf16)
    __shared__ __align__(16) float hv[4][80];
    __shared__ float bps[384];
    for (int idx = threadIdx.x; idx < 30000; idx += 384) {
        int c = idx % 75;
        int fh = (idx / 75) % 80;
        int t = idx / 6000;
        int o = t * 75 + c;
        u16 v = 0;
        if (fh < 75) v = f2bl(Wp[(t * 150 + fh) * 75 + c]);
        wpA[(fh >> 3) * 3000 + o * 8 + (fh & 7)] = v;
    }
    if (threadIdx.x < 375) bps[threadIdx.x] = bp[threadIdx.x];
    int o = threadIdx.x;
    bool act = o < 375;
    for (int vb = blockIdx.x; vb < 7500; vb += gridDim.x) {
        __syncthreads();
        if (threadIdx.x < 80) {
            int j = threadIdx.x / 20, q = threadIdx.x % 20;
            *(float4*)&hv[j][q * 4] = *(const float4*)&hN[(size_t)(vb * 4 + j) * 80 + q * 4];
        }
        __syncthreads();
        if (act) {
            float a0 = bps[o], a1 = a0, a2 = a0, a3 = a0;
#pragma unroll
            for (int cc = 0; cc < 10; cc++) {
                uint4 w = *reinterpret_cast<const uint4*>(&wpA[cc * 3000 + o * 8]);
                float w0 = __uint_as_float(w.x << 16), w1 = __uint_as_float(w.x & 0xffff0000u);
                float w2 = __uint_as_float(w.y << 16), w3 = __uint_as_float(w.y & 0xffff0000u);
                float w4 = __uint_as_float(w.z << 16), w5 = __uint_as_float(w.z & 0xffff0000u);
                float w6 = __uint_as_float(w.w << 16), w7 = __uint_as_float(w.w & 0xffff0000u);
#pragma unroll
                for (int j = 0; j < 4; j++) {
                    float4 p = *reinterpret_cast<const float4*>(&hv[j][cc * 8]);
                    float4 q = *reinterpret_cast<const float4*>(&hv[j][cc * 8 + 4]);
                    float* aj = (j == 0) ? &a0 : (j == 1) ? &a1 : (j == 2) ? &a2 : &a3;
                    float a = *aj;
                    a = fmaf(w0, p.x, a); a = fmaf(w1, p.y, a); a = fmaf(w2, p.z, a); a = fmaf(w3, p.w, a);
                    a = fmaf(w4, q.x, a); a = fmaf(w5, q.y, a); a = fmaf(w6, q.z, a); a = fmaf(w7, q.w, a);
                    *aj = a;
                }
            }
            baseb[(size_t)(vb * 4 + 0) * 384 + o] = a0;
            baseb[(size_t)(vb * 4 + 1) * 384 + o] = a1;
            baseb[(size_t)(vb * 4 + 2) * 384 + o] = a2;
            baseb[(size_t)(vb * 4 + 3) * 384 + o] = a3;
        }
    }
}

// ---------------- k_edge: per-node aggregation, packed-u32 agg out ----------------
#define EDGE_FMA(J, ACC) { \
    float4 p = *reinterpret_cast<const float4*>(&hu[J][cc * 8]); \
    float4 q = *reinterpret_cast<const float4*>(&hu[J][cc * 8 + 4]); \
    ACC = fmaf(w0, p.x, ACC); ACC = fmaf(w1, p.y, ACC); ACC = fmaf(w2, p.z, ACC); ACC = fmaf(w3, p.w, ACC); \
    ACC = fmaf(w4, q.x, ACC); ACC = fmaf(w5, q.y, ACC); ACC = fmaf(w6, q.z, ACC); ACC = fmaf(w7, q.w, ACC); }

#define STAT_UPD(A) { sum += A; sq += A * A; mn = fminf(mn, A); mx = fmaxf(mx, A); }

__global__ __launch_bounds__(384) void k_edge(const float* __restrict__ hN,
                                              const int* __restrict__ offs,
                                              const int* __restrict__ csr,
                                              const float* __restrict__ Wp,
                                              const float* __restrict__ baseb,
                                              u32* __restrict__ agg32) {
    __shared__ __align__(16) u16 wpB[30000];
    __shared__ __align__(16) float hu[4][80];
    __shared__ int su[4];
    for (int idx = threadIdx.x; idx < 30000; idx += 384) {
        int c = idx % 75;
        int fh = (idx / 75) % 80;
        int t = idx / 6000;
        int o = t * 75 + c;
        u16 v = 0;
        if (fh < 75) v = f2bl(Wp[(t * 150 + 75 + fh) * 75 + c]);
        wpB[(fh >> 3) * 3000 + o * 8 + (fh & 7)] = v;
    }
    int o = threadIdx.x;
    bool act = o < 375;
    for (int v = blockIdx.x; v < NN; v += gridDim.x) {
        int e0 = offs[v], e1 = offs[v + 1];
        float base = 0.f;
        if (act) base = baseb[(size_t)v * 384 + o];
        float sum = 0.f, sq = 0.f, mn = 3.4e38f, mx = -3.4e38f;
        for (int e = e0; e < e1; e += 4) {
            int g = e1 - e; if (g > 4) g = 4;
            __syncthreads();
            if (threadIdx.x < 4)
                su[threadIdx.x] = csr[e + (threadIdx.x < g ? threadIdx.x : g - 1)];
            __syncthreads();
            if (threadIdx.x < 80) {
                int j = threadIdx.x / 20, q = threadIdx.x % 20;
                *(float4*)&hu[j][q * 4] = *(const float4*)&hN[(size_t)su[j] * 80 + q * 4];
            }
            __syncthreads();
            if (act) {
                float a0 = base, a1 = base, a2 = base, a3 = base;
#pragma unroll
                for (int cc = 0; cc < 10; cc++) {
                    uint4 w = *reinterpret_cast<const uint4*>(&wpB[cc * 3000 + o * 8]);
                    float w0 = __uint_as_float(w.x << 16), w1 = __uint_as_float(w.x & 0xffff0000u);
                    float w2 = __uint_as_float(w.y << 16), w3 = __uint_as_float(w.y & 0xffff0000u);
                    float w4 = __uint_as_float(w.z << 16), w5 = __uint_as_float(w.z & 0xffff0000u);
                    float w6 = __uint_as_float(w.w << 16), w7 = __uint_as_float(w.w & 0xffff0000u);
                    EDGE_FMA(0, a0)
                    EDGE_FMA(1, a1)
                    EDGE_FMA(2, a2)
                    EDGE_FMA(3, a3)
                }
                STAT_UPD(a0)
                if (g > 1) STAT_UPD(a1)
                if (g > 2) STAT_UPD(a2)
                if (g > 3) STAT_UPD(a3)
            }
        }
        if (act) {
            int deg = e1 - e0;
            float cf = (float)(deg > 0 ? deg : 1);
            float mean = sum / cf, mean2 = sq / cf;
            float var = mean2 - mean * mean; if (var < 0.f) var = 0.f;
            float sd = sqrtf(var + 1e-5f);
            float mnv = deg > 0 ? mn : 0.f;
            float mxv = deg > 0 ? mx : 0.f;
            int t = o / 75, c = o % 75;
            u32* ap = agg32 + (size_t)v * 768 + t * 152;
            ap[c] = pack2(mean, mnv);        // A-words: (mean, min)
            ap[76 + c] = pack2(mxv, sd);     // B-words: (max, std)
        }
    }
}

// ---------------- k_post: thread-per-node, all 15 outputs of one tower ----------------
__global__ __launch_bounds__(256) void k_post(const float* __restrict__ hN,
                                              const int* __restrict__ offs,
                                              const u32* __restrict__ agg32,
                                              const float* __restrict__ Wq,
                                              const float* __restrict__ bq,
                                              const float* __restrict__ adl_p,
                                              float* __restrict__ tmp) {
    int t = blockIdx.x;             // tower 0..4
    int n = blockIdx.y * 256 + threadIdx.x;
    if (n >= NN) return;
    float adl = adl_p[0];
    int deg = offs[n + 1] - offs[n];
    float dc = (float)(deg > 0 ? deg : 1);
    float amp = log1pf(dc) / adl;
    float inv = 1.f / amp;
    const float* wt = Wq + (size_t)t * 975 * 15;
    float acc[15];
#pragma unroll
    for (int j = 0; j < 15; j++) acc[j] = bq[t * 15 + j];
    const float* hp = hN + (size_t)n * 80;
    for (int k = 0; k < 75; k++) {
        float in = hp[k];
        const float* wr = wt + k * 15;
#pragma unroll
        for (int j = 0; j < 15; j++) acc[j] = fmaf(in, wr[j], acc[j]);
    }
    const u32* ap = agg32 + (size_t)n * 768 + t * 152;
    for (int c = 0; c < 75; c++) {
        u32 wA = ap[c], wB = ap[76 + c];
        float vs[4];
        vs[0] = bl2f((u16)(wA & 0xffffu)); vs[1] = bl2f((u16)(wA >> 16));
        vs[2] = bl2f((u16)(wB & 0xffffu)); vs[3] = bl2f((u16)(wB >> 16));
#pragma unroll
        for (int s4 = 0; s4 < 4; s4++) {
            float a = vs[s4], aa = a * amp, ai = a * inv;
            const float* w0 = wt + (size_t)(75 + s4 * 75 + c) * 15;
            const float* w1 = wt + (size_t)(375 + s4 * 75 + c) * 15;
            const float* w2 = wt + (size_t)(675 + s4 * 75 + c) * 15;
#pragma unroll
            for (int j = 0; j < 15; j++)
                acc[j] = fmaf(a, w0[j], fmaf(aa, w1[j], fmaf(ai, w2[j], acc[j])));
        }
    }
#pragma unroll
    for (int j = 0; j < 15; j++)
        tmp[(size_t)(t * 15 + j) * NN + n] = acc[j];
}

// ---------------- W_lin + BN stats (feature-major in/out) ----------------
__global__ void k_lin(const float* __restrict__ tmp, const float* __restrict__ Wl,
                      const float* __restrict__ bl, float* __restrict__ hF,
                      float* __restrict__ bsum, float* __restrict__ bsq) {
    int c = blockIdx.x;
    int n = blockIdx.y * 256 + threadIdx.x;
    int nc = n < NN ? n : NN - 1;
    float acc = bl[c];
    for (int k = 0; k < 75; k++)
        acc = fmaf(tmp[(size_t)k * NN + nc], Wl[k * 75 + c], acc);
    bool valid = n < NN;
    if (valid) hF[(size_t)c * NN + n] = acc;
    __shared__ float s1[256], s2[256];
    s1[threadIdx.x] = valid ? acc : 0.f;
    s2[threadIdx.x] = valid ? acc * acc : 0.f;
    __syncthreads();
    for (int w = 128; w > 0; w >>= 1) {
        if (threadIdx.x < w) {
            s1[threadIdx.x] += s1[threadIdx.x + w];
            s2[threadIdx.x] += s2[threadIdx.x + w];
        }
        __syncthreads();
    }
    if (threadIdx.x == 0) {
        atomicAdd(&bsum[c], s1[0]);
        atomicAdd(&bsq[c], s2[0]);
    }
}

// ---------------- k_bn: BN + ReLU + transpose hF -> hN (node-major, pad 0) ----------------
__global__ __launch_bounds__(256) void k_bn(const float* __restrict__ hF,
                                            const float* __restrict__ bsum,
                                            const float* __restrict__ bsq,
                                            const float* __restrict__ g,
                                            const float* __restrict__ b,
                                            float* __restrict__ hN) {
    __shared__ float tile[75 * 65];
    int n0 = blockIdx.x * 64;
    int i = threadIdx.x % 64, q = threadIdx.x / 64;
    for (int c = q; c < 75; c += 4) {
        float mu = bsum[c] * (1.f / NN);
        float var = bsq[c] * (1.f / NN) - mu * mu;
        float sc = g[c] * rsqrtf(var + 1e-5f);
        int n = n0 + i;
        float v = (n < NN) ? hF[(size_t)c * NN + n] : 0.f;
        v = (v - mu) * sc + b[c];
        tile[c * 65 + i] = v > 0.f ? v : 0.f;
    }
    __syncthreads();
    int n = n0 + i;
    if (n < NN) {
        float buf[20];
#pragma unroll
        for (int w = 0; w < 20; w++) {
            int c = q * 20 + w;
            buf[w] = (c < 75) ? tile[c * 65 + i] : 0.f;
        }
        float4* dstp = (float4*)(hN + (size_t)n * 80 + q * 20);
#pragma unroll
        for (int w = 0; w < 5; w++)
            dstp[w] = make_float4(buf[4 * w], buf[4 * w + 1], buf[4 * w + 2], buf[4 * w + 3]);
    }
}

// ---------------- MLP head ----------------
__global__ __launch_bounds__(256) void k_mlp1(const float* __restrict__ hN,
                                              const float* __restrict__ alpha,
                                              const int* __restrict__ batch,
                                              const float* __restrict__ w1,
                                              const float* __restrict__ b1,
                                              float* __restrict__ t1) {
    int n = blockIdx.x * 256 + threadIdx.x;
    if (n >= NN) return;
    float acc[50];
#pragma unroll
    for (int j = 0; j < 50; j++) acc[j] = b1[j];
    const float* hp = hN + (size_t)n * 80;
    for (int k = 0; k < 75; k++) {
        float in = hp[k];
        const float* wr = w1 + k * 50;
#pragma unroll
        for (int j = 0; j < 50; j++) acc[j] = fmaf(in, wr[j], acc[j]);
    }
    float a = alpha[batch[n]];
    const float* wr = w1 + 75 * 50;
#pragma unroll
    for (int j = 0; j < 50; j++) {
        float v = fmaf(a, wr[j], acc[j]);
        t1[(size_t)j * NN + n] = v > 0.f ? v : 0.f;
    }
}

__global__ void k_mlp2(const float* __restrict__ t1, const float* __restrict__ w2,
                       const float* __restrict__ b2, const float* __restrict__ w3,
                       const float* __restrict__ b3, const float* __restrict__ noise,
                       const float* __restrict__ x, float* __restrict__ out) {
    int n = blockIdx.x * 256 + threadIdx.x;
    if (n >= NN) return;
    float tr[50];
#pragma unroll
    for (int k = 0; k < 50; k++) tr[k] = t1[(size_t)k * NN + n];
    float y = b3[0];
#pragma unroll
    for (int k2 = 0; k2 < 25; k2++) {
        float acc = b2[k2];
#pragma unroll
        for (int k = 0; k < 50; k++) acc = fmaf(tr[k], w2[k * 25 + k2], acc);
        acc = acc > 0.f ? acc : 0.f;
        y = fmaf(acc, w3[k2], y);
    }
    float z = y + noise[n];
    float s = 1.f / (1.f + expf(-z));
    out[n] = s;
    out[NN + n] = x[2 * n];   // fixed_feature passthrough (exact)
}

extern "C" void kernel_launch(void* const* d_in, const int* in_sizes, int n_in,
                              void* d_out, int out_size, void* d_ws, size_t ws_size,
                              hipStream_t stream) {
    const float* x      = (const float*)d_in[0];
    const float* alpha  = (const float*)d_in[1];
    const int*   ei     = (const int*)d_in[2];
    const int*   batch  = (const int*)d_in[3];
    const float* noise  = (const float*)d_in[4];
    const float* adl    = (const float*)d_in[5];
    const float* pre_w  = (const float*)d_in[6];
    const float* pre_b  = (const float*)d_in[7];
    const float* W_pre  = (const float*)d_in[8];
    const float* b_pre  = (const float*)d_in[9];
    const float* W_post = (const float*)d_in[10];
    const float* b_post = (const float*)d_in[11];
    const float* W_lin  = (const float*)d_in[12];
    const float* b_lin  = (const float*)d_in[13];
    const float* bn_g   = (const float*)d_in[14];
    const float* bn_b   = (const float*)d_in[15];
    const float* mw1    = (const float*)d_in[16];
    const float* mb1    = (const float*)d_in[17];
    const float* mw2    = (const float*)d_in[18];
    const float* mb2    = (const float*)d_in[19];
    const float* mw3    = (const float*)d_in[20];
    const float* mb3    = (const float*)d_in[21];
    (void)in_sizes; (void)n_in; (void)out_size; (void)ws_size;

    char* ws = (char*)d_ws;
    size_t off = 0;
    auto alloc = [&](size_t bytes) -> char* {
        char* p = ws + off;
        off += (bytes + 255) & ~((size_t)255);
        return p;
    };
    float* hN    = (float*)alloc((size_t)NN * 80 * 4);       // node-major h, pad 0
    float* hF    = (float*)alloc((size_t)75 * NN * 4);       // feature-major (BN staging)
    float* tmp   = (float*)alloc((size_t)75 * NN * 4);       // [75][N], reused as t1
    u32*   agg32 = (u32*)alloc((size_t)NN * 768 * 4);        // packed bf16 pairs
    float* baseb = (float*)alloc((size_t)NN * 384 * 4);      // f32
    int*   cnt   = (int*)alloc((size_t)NN * 4);
    int*   offs  = (int*)alloc((size_t)(NN + 1) * 4);
    int*   fill  = (int*)alloc((size_t)NN * 4);
    int*   csr   = (int*)alloc((size_t)EE * 4);
    float* bnsum = (float*)alloc(4 * 75 * 4);
    float* bnsq  = (float*)alloc(4 * 75 * 4);

    hipMemsetAsync(cnt, 0, (size_t)NN * 4, stream);
    hipMemsetAsync(fill, 0, (size_t)NN * 4, stream);
    hipMemsetAsync(bnsum, 0, 4 * 75 * 4, stream);
    hipMemsetAsync(bnsq, 0, 4 * 75 * 4, stream);

    const int* src = ei;
    const int* dst = ei + EE;
    int eb = (EE + 255) / 256;
    int nb = (NN + 255) / 256;
    int tb = (NN + 63) / 64;

    k_count<<<eb, 256, 0, stream>>>(dst, cnt);
    k_scan<<<1, 1024, 0, stream>>>(cnt, offs);
    k_scatter<<<eb, 256, 0, stream>>>(src, dst, offs, fill, csr);
    k_pre<<<nb, 256, 0, stream>>>(x, pre_w, pre_b, hN);

    for (int l = 0; l < 4; l++) {
        const float* Wp  = W_pre + (size_t)l * 5 * 150 * 75;
        const float* bp  = b_pre + l * 375;
        const float* Wq  = W_post + (size_t)l * 5 * 975 * 15;
        const float* bq  = b_post + l * 75;
        const float* Wl  = W_lin + l * 75 * 75;
        const float* blp = b_lin + l * 75;
        k_base<<<1024, 384, 0, stream>>>(hN, Wp, bp, baseb);
        k_edge<<<1024, 384, 0, stream>>>(hN, offs, csr, Wp, baseb, agg32);
        k_post<<<dim3(5, nb), 256, 0, stream>>>(hN, offs, agg32, Wq, bq, adl, tmp);
        k_lin<<<dim3(75, nb), 256, 0, stream>>>(tmp, Wl, blp, hF, bnsum + l * 75, bnsq + l * 75);
        k_bn<<<tb, 256, 0, stream>>>(hF, bnsum + l * 75, bnsq + l * 75,
                                     bn_g + l * 75, bn_b + l * 75, hN);
    }

    float* t1 = tmp;
    k_mlp1<<<nb, 256, 0, stream>>>(hN, alpha, batch, mw1, mb1, t1);
    k_mlp2<<<nb, 256, 0, stream>>>(t1, mw2, mb2, mw3, mb3, noise, x, (float*)d_out);
}

// Round 5
// 7973.952 us; speedup vs baseline: 1.3689x; 1.1633x over previous
//
#include <hip/hip_runtime.h>
#include <hip/hip_bf16.h>
#include <cstdint>
#include <cstddef>

#define NN 30000
#define EE 150000
#define NCH 15000   // nodes per chunk (2 chunks)
#define ECH 80000   // m32 rows budget per chunk (~75000 expected, +25 sigma)

using u16 = unsigned short;
using u32 = unsigned int;

__device__ __forceinline__ float bl2f(u16 u) { return __uint_as_float(((u32)u) << 16); }
__device__ __forceinline__ u16 f2bl(float f) {
    u32 x = __float_as_uint(f);
    return (u16)((x + 0x7fffu + ((x >> 16) & 1u)) >> 16);
}
__device__ __forceinline__ u32 pack2(float a, float b) {
    return (u32)f2bl(a) | ((u32)f2bl(b) << 16);
}

// ---------------- CSR build ----------------
__global__ void k_count(const int* __restrict__ dst, int* __restrict__ cnt) {
    int e = blockIdx.x * 256 + threadIdx.x;
    if (e < EE) atomicAdd(&cnt[dst[e]], 1);
}

__global__ void k_scan(const int* __restrict__ cnt, int* __restrict__ offs) {
    __shared__ int ss[1024];
    int t = threadIdx.x;
    int base = t * 30;
    int s = 0;
    for (int i = 0; i < 30; i++) { int idx = base + i; if (idx < NN) s += cnt[idx]; }
    ss[t] = s; __syncthreads();
    for (int off = 1; off < 1024; off <<= 1) {
        int v = (t >= off) ? ss[t - off] : 0;
        __syncthreads();
        ss[t] += v;
        __syncthreads();
    }
    int run = (t == 0) ? 0 : ss[t - 1];
    for (int i = 0; i < 30; i++) {
        int idx = base + i;
        if (idx < NN) { offs[idx] = run; run += cnt[idx]; }
    }
    if (t == 1023) offs[NN] = run;
}

__global__ void k_scatter(const int* __restrict__ src, const int* __restrict__ dst,
                          const int* __restrict__ offs, int* __restrict__ fill,
                          int* __restrict__ csr) {
    int e = blockIdx.x * 256 + threadIdx.x;
    if (e < EE) {
        int d = dst[e];
        int p = offs[d] + atomicAdd(&fill[d], 1);
        csr[p] = src[e];
    }
}

// ---------------- pre linear: hN[n][80] ----------------
__global__ void k_pre(const float* __restrict__ x, const float* __restrict__ pw,
                      const float* __restrict__ pb, float* __restrict__ hN) {
    int n = blockIdx.x * 256 + threadIdx.x;
    if (n >= NN) return;
    float x0 = x[2 * n], x1 = x[2 * n + 1];
    float buf[80];
#pragma unroll
    for (int c = 0; c < 80; c++)
        buf[c] = (c < 75) ? fmaf(x0, pw[c], fmaf(x1, pw[75 + c], pb[c])) : 0.f;
    float4* dstp = (float4*)(hN + (size_t)n * 80);
#pragma unroll
    for (int w = 0; w < 20; w++)
        dstp[w] = make_float4(buf[4 * w], buf[4 * w + 1], buf[4 * w + 2], buf[4 * w + 3]);
}

// ---------------- k_base: dst-half GEMM per node -> bf16-pair baseb32[v][188] --------
__global__ __launch_bounds__(384) void k_base(const float* __restrict__ hN,
                                              const float* __restrict__ Wp,
                                              const float* __restrict__ bp,
                                              u32* __restrict__ baseb32) {
    __shared__ __align__(16) u16 wpA[30000];
    __shared__ __align__(16) float hv[4][80];
    __shared__ float bps[384];
    for (int idx = threadIdx.x; idx < 30000; idx += 384) {
        int c = idx % 75;
        int fh = (idx / 75) % 80;
        int t = idx / 6000;
        int o = t * 75 + c;
        u16 v = 0;
        if (fh < 75) v = f2bl(Wp[(t * 150 + fh) * 75 + c]);
        wpA[(fh >> 3) * 3000 + o * 8 + (fh & 7)] = v;
    }
    bps[threadIdx.x] = (threadIdx.x < 375) ? bp[threadIdx.x] : 0.f;
    int o = threadIdx.x;
    int oc = o < 375 ? o : 374;
    bool store_lane = ((o & 1) == 0) && (o < 375);
    for (int vb = blockIdx.x; vb < 7500; vb += gridDim.x) {
        __syncthreads();
        if (threadIdx.x < 80) {
            int j = threadIdx.x / 20, q = threadIdx.x % 20;
            *(float4*)&hv[j][q * 4] = *(const float4*)&hN[(size_t)(vb * 4 + j) * 80 + q * 4];
        }
        __syncthreads();
        float accs[4];
#pragma unroll
        for (int j = 0; j < 4; j++) accs[j] = bps[o];
#pragma unroll
        for (int cc = 0; cc < 10; cc++) {
            uint4 w = *reinterpret_cast<const uint4*>(&wpA[cc * 3000 + oc * 8]);
            float w0 = __uint_as_float(w.x << 16), w1 = __uint_as_float(w.x & 0xffff0000u);
            float w2 = __uint_as_float(w.y << 16), w3 = __uint_as_float(w.y & 0xffff0000u);
            float w4 = __uint_as_float(w.z << 16), w5 = __uint_as_float(w.z & 0xffff0000u);
            float w6 = __uint_as_float(w.w << 16), w7 = __uint_as_float(w.w & 0xffff0000u);
#pragma unroll
            for (int j = 0; j < 4; j++) {
                float4 p = *reinterpret_cast<const float4*>(&hv[j][cc * 8]);
                float4 q4 = *reinterpret_cast<const float4*>(&hv[j][cc * 8 + 4]);
                float a = accs[j];
                a = fmaf(w0, p.x, a); a = fmaf(w1, p.y, a); a = fmaf(w2, p.z, a); a = fmaf(w3, p.w, a);
                a = fmaf(w4, q4.x, a); a = fmaf(w5, q4.y, a); a = fmaf(w6, q4.z, a); a = fmaf(w7, q4.w, a);
                accs[j] = a;
            }
        }
#pragma unroll
        for (int j = 0; j < 4; j++) {
            u32 mine = (o < 375) ? (u32)f2bl(accs[j]) : 0u;
            u32 up = (u32)__shfl_down((int)mine, 1);
            if (store_lane)
                baseb32[(size_t)(vb * 4 + j) * 188 + (o >> 1)] = mine | (up << 16);
        }
    }
}

// ---------------- k_msg: edge-parallel message GEMM for CSR slots of [n0,n1) --------
__global__ __launch_bounds__(384) void k_msg(const float* __restrict__ hN,
                                             const int* __restrict__ csr,
                                             const float* __restrict__ Wp,
                                             u32* __restrict__ m32,
                                             const int* __restrict__ offs,
                                             int n0, int n1) {
    __shared__ __align__(16) u16 wpB[30000];
    __shared__ __align__(16) u32 hu32[8][40];
    __shared__ int su[8];
    for (int idx = threadIdx.x; idx < 30000; idx += 384) {
        int c = idx % 75;
        int fh = (idx / 75) % 80;
        int t = idx / 6000;
        int o = t * 75 + c;
        u16 v = 0;
        if (fh < 75) v = f2bl(Wp[(t * 150 + 75 + fh) * 75 + c]);
        wpB[(fh >> 3) * 3000 + o * 8 + (fh & 7)] = v;
    }
    int e_begin = offs[n0], e_end = offs[n1];
    int nP = (e_end - e_begin + 7) >> 3;
    int o = threadIdx.x;
    int oc = o < 375 ? o : 374;
    bool store_lane = ((o & 1) == 0) && (o < 375);
    for (int p = blockIdx.x; p < nP; p += gridDim.x) {
        __syncthreads();
        if (threadIdx.x < 8) {
            int slot = e_begin + p * 8 + threadIdx.x;
            su[threadIdx.x] = csr[slot < e_end ? slot : e_end - 1];
        }
        __syncthreads();
        if (threadIdx.x < 320) {
            int j = threadIdx.x / 40, k = threadIdx.x % 40;
            float2 hvv = *(const float2*)&hN[(size_t)su[j] * 80 + 2 * k];
            hu32[j][k] = pack2(hvv.x, hvv.y);
        }
        __syncthreads();
        float accs[8] = {0.f, 0.f, 0.f, 0.f, 0.f, 0.f, 0.f, 0.f};
#pragma unroll
        for (int cc = 0; cc < 10; cc++) {
            uint4 w = *reinterpret_cast<const uint4*>(&wpB[cc * 3000 + oc * 8]);
            float w0 = __uint_as_float(w.x << 16), w1 = __uint_as_float(w.x & 0xffff0000u);
            float w2 = __uint_as_float(w.y << 16), w3 = __uint_as_float(w.y & 0xffff0000u);
            float w4 = __uint_as_float(w.z << 16), w5 = __uint_as_float(w.z & 0xffff0000u);
            float w6 = __uint_as_float(w.w << 16), w7 = __uint_as_float(w.w & 0xffff0000u);
#pragma unroll
            for (int j = 0; j < 8; j++) {
                uint4 a = *reinterpret_cast<const uint4*>(&hu32[j][cc * 4]);
                float h0 = __uint_as_float(a.x << 16), h1 = __uint_as_float(a.x & 0xffff0000u);
                float h2 = __uint_as_float(a.y << 16), h3 = __uint_as_float(a.y & 0xffff0000u);
                float h4 = __uint_as_float(a.z << 16), h5 = __uint_as_float(a.z & 0xffff0000u);
                float h6 = __uint_as_float(a.w << 16), h7 = __uint_as_float(a.w & 0xffff0000u);
                float acc = accs[j];
                acc = fmaf(w0, h0, acc); acc = fmaf(w1, h1, acc); acc = fmaf(w2, h2, acc); acc = fmaf(w3, h3, acc);
                acc = fmaf(w4, h4, acc); acc = fmaf(w5, h5, acc); acc = fmaf(w6, h6, acc); acc = fmaf(w7, h7, acc);
                accs[j] = acc;
            }
        }
#pragma unroll
        for (int j = 0; j < 8; j++) {
            u32 mine = (o < 375) ? (u32)f2bl(accs[j]) : 0u;
            u32 up = (u32)__shfl_down((int)mine, 1);
            int row = p * 8 + j;
            if (store_lane && (e_begin + row) < e_end)
                m32[(size_t)row * 188 + (o >> 1)] = mine | (up << 16);
        }
    }
}

// ---------------- k_agg: per-node stats over chunk-relative m32 rows ----------------
__global__ __launch_bounds__(192) void k_agg(const u32* __restrict__ m32,
                                             const int* __restrict__ offs,
                                             const u32* __restrict__ baseb32,
                                             u32* __restrict__ agg32,
                                             int n0, int n1) {
    int q = threadIdx.x;
    if (q >= 188) return;  // no barriers below
    int e_base = offs[n0];
    int o0 = 2 * q, o1 = 2 * q + 1;
    bool has1 = o1 < 375;
    int t0 = o0 / 75, c0 = o0 % 75;
    int t1 = has1 ? (o1 / 75) : 0, c1 = has1 ? (o1 % 75) : 0;
    for (int v = n0 + blockIdx.x; v < n1; v += gridDim.x) {
        int e0 = offs[v], e1 = offs[v + 1];
        float s0 = 0.f, s1 = 0.f, sq0 = 0.f, sq1 = 0.f;
        float mn0 = 3.4e38f, mn1 = 3.4e38f, mx0 = -3.4e38f, mx1 = -3.4e38f;
        for (int e = e0; e < e1; e++) {
            u32 w = m32[(size_t)(e - e_base) * 188 + q];
            float x0 = bl2f((u16)(w & 0xffffu)), x1 = bl2f((u16)(w >> 16));
            s0 += x0; sq0 = fmaf(x0, x0, sq0); mn0 = fminf(mn0, x0); mx0 = fmaxf(mx0, x0);
            s1 += x1; sq1 = fmaf(x1, x1, sq1); mn1 = fminf(mn1, x1); mx1 = fmaxf(mx1, x1);
        }
        int deg = e1 - e0;
        u32 bw = baseb32[(size_t)v * 188 + q];
        float b0 = bl2f((u16)(bw & 0xffffu)), b1 = bl2f((u16)(bw >> 16));
        float mean0, mean1, mnf0, mnf1, mxf0, mxf1, sd0, sd1;
        if (deg > 0) {
            float im = 1.f / (float)deg;
            float mm0 = s0 * im, mm1 = s1 * im;
            float v0 = fmaxf(fmaf(-mm0, mm0, sq0 * im), 0.f);
            float v1 = fmaxf(fmaf(-mm1, mm1, sq1 * im), 0.f);
            sd0 = sqrtf(v0 + 1e-5f); sd1 = sqrtf(v1 + 1e-5f);
            mean0 = b0 + mm0; mean1 = b1 + mm1;
            mnf0 = b0 + mn0;  mnf1 = b1 + mn1;
            mxf0 = b0 + mx0;  mxf1 = b1 + mx1;
        } else {
            float sde = sqrtf(1e-5f);
            mean0 = mean1 = mnf0 = mnf1 = mxf0 = mxf1 = 0.f;
            sd0 = sd1 = sde;
        }
        u32* ap = agg32 + (size_t)(v - n0) * 768;
        ap[t0 * 152 + c0] = pack2(mean0, mnf0);
        ap[t0 * 152 + 76 + c0] = pack2(mxf0, sd0);
        if (has1) {
            ap[t1 * 152 + c1] = pack2(mean1, mnf1);
            ap[t1 * 152 + 76 + c1] = pack2(mxf1, sd1);
        }
    }
}

// ---------------- k_post: thread-per-node, one tower, chunked ----------------
__global__ __launch_bounds__(256) void k_post(const float* __restrict__ hN,
                                              const int* __restrict__ offs,
                                              const u32* __restrict__ agg32,
                                              const float* __restrict__ Wq,
                                              const float* __restrict__ bq,
                                              const float* __restrict__ adl_p,
                                              float* __restrict__ tmp,
                                              int n0, int n1) {
    int t = blockIdx.x;
    int n = n0 + blockIdx.y * 256 + threadIdx.x;
    if (n >= n1) return;
    float adl = adl_p[0];
    int deg = offs[n + 1] - offs[n];
    float dc = (float)(deg > 0 ? deg : 1);
    float amp = log1pf(dc) / adl;
    float inv = 1.f / amp;
    const float* wt = Wq + (size_t)t * 975 * 15;
    float acc[15];
#pragma unroll
    for (int j = 0; j < 15; j++) acc[j] = bq[t * 15 + j];
    const float* hp = hN + (size_t)n * 80;
    for (int k = 0; k < 75; k++) {
        float in = hp[k];
        const float* wr = wt + k * 15;
#pragma unroll
        for (int j = 0; j < 15; j++) acc[j] = fmaf(in, wr[j], acc[j]);
    }
    const u32* ap = agg32 + (size_t)(n - n0) * 768 + t * 152;
    for (int c = 0; c < 75; c++) {
        u32 wA = ap[c], wB = ap[76 + c];
        float vs[4];
        vs[0] = bl2f((u16)(wA & 0xffffu)); vs[1] = bl2f((u16)(wA >> 16));
        vs[2] = bl2f((u16)(wB & 0xffffu)); vs[3] = bl2f((u16)(wB >> 16));
#pragma unroll
        for (int s4 = 0; s4 < 4; s4++) {
            float a = vs[s4], aa = a * amp, ai = a * inv;
            const float* w0 = wt + (size_t)(75 + s4 * 75 + c) * 15;
            const float* w1 = wt + (size_t)(375 + s4 * 75 + c) * 15;
            const float* w2 = wt + (size_t)(675 + s4 * 75 + c) * 15;
#pragma unroll
            for (int j = 0; j < 15; j++)
                acc[j] = fmaf(a, w0[j], fmaf(aa, w1[j], fmaf(ai, w2[j], acc[j])));
        }
    }
#pragma unroll
    for (int j = 0; j < 15; j++)
        tmp[(size_t)(t * 15 + j) * NN + n] = acc[j];
}

// ---------------- k_lin2: thread-per-node 75x75 linear + BN stats ----------------
__global__ __launch_bounds__(256) void k_lin2(const float* __restrict__ tmp,
                                              const float* __restrict__ Wl,
                                              const float* __restrict__ bl,
                                              float* __restrict__ zN,
                                              float* __restrict__ bsum,
                                              float* __restrict__ bsq) {
    int n = blockIdx.x * 256 + threadIdx.x;
    bool valid = n < NN;
    int nc = valid ? n : NN - 1;
    float acc[75];
#pragma unroll
    for (int c = 0; c < 75; c++) acc[c] = bl[c];
    for (int k = 0; k < 75; k++) {
        float in = tmp[(size_t)k * NN + nc];
        const float* wr = Wl + k * 75;
#pragma unroll
        for (int c = 0; c < 75; c++) acc[c] = fmaf(in, wr[c], acc[c]);
    }
    if (valid) {
        float4* dstp = (float4*)(zN + (size_t)n * 80);
#pragma unroll
        for (int w = 0; w < 18; w++)
            dstp[w] = make_float4(acc[4 * w], acc[4 * w + 1], acc[4 * w + 2], acc[4 * w + 3]);
        dstp[18] = make_float4(acc[72], acc[73], acc[74], 0.f);
        dstp[19] = make_float4(0.f, 0.f, 0.f, 0.f);
    }
    int lane = threadIdx.x & 63;
    for (int c0 = 0; c0 < 75; c0 += 15) {
        float s[15], ss[15];
#pragma unroll
        for (int i = 0; i < 15; i++) {
            float a = valid ? acc[c0 + i] : 0.f;
            s[i] = a; ss[i] = a * a;
        }
        for (int d = 32; d > 0; d >>= 1) {
#pragma unroll
            for (int i = 0; i < 15; i++) {
                s[i] += __shfl_down(s[i], d);
                ss[i] += __shfl_down(ss[i], d);
            }
        }
        if (lane == 0) {
#pragma unroll
            for (int i = 0; i < 15; i++) {
                atomicAdd(&bsum[c0 + i], s[i]);
                atomicAdd(&bsq[c0 + i], ss[i]);
            }
        }
    }
}

// ---------------- k_bn2: BN + ReLU node-major zN -> hN ----------------
__global__ __launch_bounds__(256) void k_bn2(const float* __restrict__ zN,
                                             const float* __restrict__ bsum,
                                             const float* __restrict__ bsq,
                                             const float* __restrict__ g,
                                             const float* __restrict__ b,
                                             float* __restrict__ hN) {
    int n = blockIdx.x * 256 + threadIdx.x;
    if (n >= NN) return;
    const float* zp = zN + (size_t)n * 80;
    float buf[80];
#pragma unroll
    for (int c = 0; c < 75; c++) {
        float mu = bsum[c] * (1.f / NN);
        float var = bsq[c] * (1.f / NN) - mu * mu;
        float sc = g[c] * rsqrtf(var + 1e-5f);
        float v = (zp[c] - mu) * sc + b[c];
        buf[c] = v > 0.f ? v : 0.f;
    }
#pragma unroll
    for (int c = 75; c < 80; c++) buf[c] = 0.f;
    float4* dstp = (float4*)(hN + (size_t)n * 80);
#pragma unroll
    for (int w = 0; w < 20; w++)
        dstp[w] = make_float4(buf[4 * w], buf[4 * w + 1], buf[4 * w + 2], buf[4 * w + 3]);
}

// ---------------- MLP head ----------------
__global__ __launch_bounds__(256) void k_mlp1(const float* __restrict__ hN,
                                              const float* __restrict__ alpha,
                                              const int* __restrict__ batch,
                                              const float* __restrict__ w1,
                                              const float* __restrict__ b1,
                                              float* __restrict__ t1) {
    int n = blockIdx.x * 256 + threadIdx.x;
    if (n >= NN) return;
    float acc[50];
#pragma unroll
    for (int j = 0; j < 50; j++) acc[j] = b1[j];
    const float* hp = hN + (size_t)n * 80;
    for (int k = 0; k < 75; k++) {
        float in = hp[k];
        const float* wr = w1 + k * 50;
#pragma unroll
        for (int j = 0; j < 50; j++) acc[j] = fmaf(in, wr[j], acc[j]);
    }
    float a = alpha[batch[n]];
    const float* wr = w1 + 75 * 50;
#pragma unroll
    for (int j = 0; j < 50; j++) {
        float v = fmaf(a, wr[j], acc[j]);
        t1[(size_t)j * NN + n] = v > 0.f ? v : 0.f;
    }
}

__global__ void k_mlp2(const float* __restrict__ t1, const float* __restrict__ w2,
                       const float* __restrict__ b2, const float* __restrict__ w3,
                       const float* __restrict__ b3, const float* __restrict__ noise,
                       const float* __restrict__ x, float* __restrict__ out) {
    int n = blockIdx.x * 256 + threadIdx.x;
    if (n >= NN) return;
    float tr[50];
#pragma unroll
    for (int k = 0; k < 50; k++) tr[k] = t1[(size_t)k * NN + n];
    float y = b3[0];
#pragma unroll
    for (int k2 = 0; k2 < 25; k2++) {
        float acc = b2[k2];
#pragma unroll
        for (int k = 0; k < 50; k++) acc = fmaf(tr[k], w2[k * 25 + k2], acc);
        acc = acc > 0.f ? acc : 0.f;
        y = fmaf(acc, w3[k2], y);
    }
    float z = y + noise[n];
    float s = 1.f / (1.f + expf(-z));
    out[n] = s;
    out[NN + n] = x[2 * n];
}

extern "C" void kernel_launch(void* const* d_in, const int* in_sizes, int n_in,
                              void* d_out, int out_size, void* d_ws, size_t ws_size,
                              hipStream_t stream) {
    const float* x      = (const float*)d_in[0];
    const float* alpha  = (const float*)d_in[1];
    const int*   ei     = (const int*)d_in[2];
    const int*   batch  = (const int*)d_in[3];
    const float* noise  = (const float*)d_in[4];
    const float* adl    = (const float*)d_in[5];
    const float* pre_w  = (const float*)d_in[6];
    const float* pre_b  = (const float*)d_in[7];
    const float* W_pre  = (const float*)d_in[8];
    const float* b_pre  = (const float*)d_in[9];
    const float* W_post = (const float*)d_in[10];
    const float* b_post = (const float*)d_in[11];
    const float* W_lin  = (const float*)d_in[12];
    const float* b_lin  = (const float*)d_in[13];
    const float* bn_g   = (const float*)d_in[14];
    const float* bn_b   = (const float*)d_in[15];
    const float* mw1    = (const float*)d_in[16];
    const float* mb1    = (const float*)d_in[17];
    const float* mw2    = (const float*)d_in[18];
    const float* mb2    = (const float*)d_in[19];
    const float* mw3    = (const float*)d_in[20];
    const float* mb3    = (const float*)d_in[21];
    (void)in_sizes; (void)n_in; (void)out_size; (void)ws_size;

    char* ws = (char*)d_ws;
    size_t off = 0;
    auto alloc = [&](size_t bytes) -> char* {
        char* p = ws + off;
        off += (bytes + 255) & ~((size_t)255);
        return p;
    };
    // total ~158 MB (known-good: 166 MB passed in R3)
    float* hN     = (float*)alloc((size_t)NN * 80 * 4);        //  9.6 MB
    float* zN     = (float*)alloc((size_t)NN * 80 * 4);        //  9.6 MB
    float* tmp    = (float*)alloc((size_t)75 * NN * 4);        //  9.0 MB
    u32*   agg32  = (u32*)alloc((size_t)NCH * 768 * 4);        // 46.1 MB (per-chunk)
    u32*   baseb32= (u32*)alloc((size_t)NN * 188 * 4);         // 22.6 MB (bf16 pairs)
    u32*   m32    = (u32*)alloc((size_t)ECH * 188 * 4);        // 60.2 MB (per-chunk)
    int*   cnt    = (int*)alloc((size_t)NN * 4);
    int*   offs   = (int*)alloc((size_t)(NN + 1) * 4);
    int*   fill   = (int*)alloc((size_t)NN * 4);
    int*   csr    = (int*)alloc((size_t)EE * 4);
    float* bnsum  = (float*)alloc(4 * 75 * 4);
    float* bnsq   = (float*)alloc(4 * 75 * 4);

    hipMemsetAsync(cnt, 0, (size_t)NN * 4, stream);
    hipMemsetAsync(fill, 0, (size_t)NN * 4, stream);
    hipMemsetAsync(bnsum, 0, 4 * 75 * 4, stream);
    hipMemsetAsync(bnsq, 0, 4 * 75 * 4, stream);

    const int* src = ei;
    const int* dst = ei + EE;
    int eb = (EE + 255) / 256;
    int nb = (NN + 255) / 256;
    int cb = (NCH + 255) / 256;

    k_count<<<eb, 256, 0, stream>>>(dst, cnt);
    k_scan<<<1, 1024, 0, stream>>>(cnt, offs);
    k_scatter<<<eb, 256, 0, stream>>>(src, dst, offs, fill, csr);
    k_pre<<<nb, 256, 0, stream>>>(x, pre_w, pre_b, hN);

    for (int l = 0; l < 4; l++) {
        const float* Wp  = W_pre + (size_t)l * 5 * 150 * 75;
        const float* bp  = b_pre + l * 375;
        const float* Wq  = W_post + (size_t)l * 5 * 975 * 15;
        const float* bq  = b_post + l * 75;
        const float* Wl  = W_lin + l * 75 * 75;
        const float* blp = b_lin + l * 75;
        k_base<<<1024, 384, 0, stream>>>(hN, Wp, bp, baseb32);
        for (int ch = 0; ch < 2; ch++) {
            int n0 = ch * NCH, n1 = n0 + NCH;
            k_msg<<<512, 384, 0, stream>>>(hN, csr, Wp, m32, offs, n0, n1);
            k_agg<<<2048, 192, 0, stream>>>(m32, offs, baseb32, agg32, n0, n1);
            k_post<<<dim3(5, cb), 256, 0, stream>>>(hN, offs, agg32, Wq, bq, adl, tmp, n0, n1);
        }
        k_lin2<<<nb, 256, 0, stream>>>(tmp, Wl, blp, zN, bnsum + l * 75, bnsq + l * 75);
        k_bn2<<<nb, 256, 0, stream>>>(zN, bnsum + l * 75, bnsq + l * 75,
                                      bn_g + l * 75, bn_b + l * 75, hN);
    }

    float* t1 = tmp;
    k_mlp1<<<nb, 256, 0, stream>>>(hN, alpha, batch, mw1, mb1, t1);
    k_mlp2<<<nb, 256, 0, stream>>>(t1, mw2, mb2, mw3, mb3, noise, x, (float*)d_out);
}

// Round 6
// 3680.046 us; speedup vs baseline: 2.9662x; 2.1668x over previous
//
#include <hip/hip_runtime.h>
#include <hip/hip_bf16.h>
#include <cstdint>
#include <cstddef>

#define NN 30000
#define EE 150000
#define NCH 15000   // nodes per chunk (2 chunks)
#define ECH 80000   // m32 rows budget per chunk (~75000 expected)

using u16 = unsigned short;
using u32 = unsigned int;

__device__ __forceinline__ float bl2f(u16 u) { return __uint_as_float(((u32)u) << 16); }
__device__ __forceinline__ u16 f2bl(float f) {
    u32 x = __float_as_uint(f);
    return (u16)((x + 0x7fffu + ((x >> 16) & 1u)) >> 16);
}
__device__ __forceinline__ u32 pack2(float a, float b) {
    return (u32)f2bl(a) | ((u32)f2bl(b) << 16);
}

// ---------------- CSR build ----------------
__global__ void k_count(const int* __restrict__ dst, int* __restrict__ cnt) {
    int e = blockIdx.x * 256 + threadIdx.x;
    if (e < EE) atomicAdd(&cnt[dst[e]], 1);
}

__global__ void k_scan(const int* __restrict__ cnt, int* __restrict__ offs) {
    __shared__ int ss[1024];
    int t = threadIdx.x;
    int base = t * 30;
    int s = 0;
    for (int i = 0; i < 30; i++) { int idx = base + i; if (idx < NN) s += cnt[idx]; }
    ss[t] = s; __syncthreads();
    for (int off = 1; off < 1024; off <<= 1) {
        int v = (t >= off) ? ss[t - off] : 0;
        __syncthreads();
        ss[t] += v;
        __syncthreads();
    }
    int run = (t == 0) ? 0 : ss[t - 1];
    for (int i = 0; i < 30; i++) {
        int idx = base + i;
        if (idx < NN) { offs[idx] = run; run += cnt[idx]; }
    }
    if (t == 1023) offs[NN] = run;
}

__global__ void k_scatter(const int* __restrict__ src, const int* __restrict__ dst,
                          const int* __restrict__ offs, int* __restrict__ fill,
                          int* __restrict__ csr) {
    int e = blockIdx.x * 256 + threadIdx.x;
    if (e < EE) {
        int d = dst[e];
        int p = offs[d] + atomicAdd(&fill[d], 1);
        csr[p] = src[e];
    }
}

// ---------------- pre linear: hN[n][80] ----------------
__global__ void k_pre(const float* __restrict__ x, const float* __restrict__ pw,
                      const float* __restrict__ pb, float* __restrict__ hN) {
    int n = blockIdx.x * 256 + threadIdx.x;
    if (n >= NN) return;
    float x0 = x[2 * n], x1 = x[2 * n + 1];
    float buf[80];
#pragma unroll
    for (int c = 0; c < 80; c++)
        buf[c] = (c < 75) ? fmaf(x0, pw[c], fmaf(x1, pw[75 + c], pb[c])) : 0.f;
    float4* dstp = (float4*)(hN + (size_t)n * 80);
#pragma unroll
    for (int w = 0; w < 20; w++)
        dstp[w] = make_float4(buf[4 * w], buf[4 * w + 1], buf[4 * w + 2], buf[4 * w + 3]);
}

// ---- shared inner: 30 outputs (two 15-chunks) of h(75) x Wp, wave-uniform weights ----
__device__ __forceinline__ void gemm30(const float* __restrict__ hp,
                                       const float* __restrict__ wA,
                                       const float* __restrict__ wB,
                                       float* acc) {
    for (int fq = 0; fq < 18; fq++) {
        float4 h4 = *(const float4*)(hp + fq * 4);
        const float* ra = wA + fq * 300;
        const float* rb = wB + fq * 300;
#pragma unroll
        for (int k = 0; k < 4; k++) {
            float in = (k == 0) ? h4.x : (k == 1) ? h4.y : (k == 2) ? h4.z : h4.w;
#pragma unroll
            for (int j = 0; j < 15; j++) acc[j] = fmaf(in, ra[k * 75 + j], acc[j]);
#pragma unroll
            for (int j = 0; j < 15; j++) acc[15 + j] = fmaf(in, rb[k * 75 + j], acc[15 + j]);
        }
    }
#pragma unroll
    for (int f = 72; f < 75; f++) {
        float in = hp[f];
#pragma unroll
        for (int j = 0; j < 15; j++) acc[j] = fmaf(in, wA[f * 75 + j], acc[j]);
#pragma unroll
        for (int j = 0; j < 15; j++) acc[15 + j] = fmaf(in, wB[f * 75 + j], acc[15 + j]);
    }
}

// ---------------- k_base: thread-per-node x 13 pair-chunks -> baseb32[n][188] --------
__global__ __launch_bounds__(256) void k_base(const float* __restrict__ hN,
                                              const float* __restrict__ Wp,
                                              const float* __restrict__ bp,
                                              u32* __restrict__ baseb32) {
    int n = blockIdx.x * 256 + threadIdx.x;
    int p = blockIdx.y;               // 0..12, block-uniform
    if (n >= NN) return;
    const float* hp = hN + (size_t)n * 80;
    int o0 = p * 30;
    int cg = p * 2;
    int tA = cg / 5, cA = (cg % 5) * 15;
    bool full = p < 12;
    int cg1 = full ? cg + 1 : cg;
    int tB = cg1 / 5, cB = (cg1 % 5) * 15;
    float acc[30];
#pragma unroll
    for (int j = 0; j < 15; j++) acc[j] = bp[o0 + j];
#pragma unroll
    for (int j = 0; j < 15; j++) acc[15 + j] = full ? bp[o0 + 15 + j] : 0.f;
    const float* wA = Wp + (size_t)tA * 150 * 75 + cA;
    const float* wB = Wp + (size_t)tB * 150 * 75 + cB;
    gemm30(hp, wA, wB, acc);
    u32* row = baseb32 + (size_t)n * 188 + p * 15;
    if (full) {
#pragma unroll
        for (int w = 0; w < 15; w++) row[w] = pack2(acc[2 * w], acc[2 * w + 1]);
    } else {
#pragma unroll
        for (int w = 0; w < 7; w++) row[w] = pack2(acc[2 * w], acc[2 * w + 1]);
        row[7] = pack2(acc[14], 0.f);
    }
}

// ---------------- k_msg: thread-per-edge x 13 pair-chunks -> m32[row][188] ----------
__global__ __launch_bounds__(256) void k_msg(const float* __restrict__ hN,
                                             const int* __restrict__ csr,
                                             const float* __restrict__ Wp,
                                             u32* __restrict__ m32,
                                             const int* __restrict__ offs,
                                             int n0, int n1) {
    int e_begin = offs[n0], e_end = offs[n1];
    int e = e_begin + blockIdx.x * 256 + threadIdx.x;
    if (e >= e_end) return;
    int p = blockIdx.y;               // 0..12, block-uniform
    int su = csr[e];
    const float* hp = hN + (size_t)su * 80;
    int cg = p * 2;
    int tA = cg / 5, cA = (cg % 5) * 15;
    bool full = p < 12;
    int cg1 = full ? cg + 1 : cg;
    int tB = cg1 / 5, cB = (cg1 % 5) * 15;
    float acc[30];
#pragma unroll
    for (int j = 0; j < 30; j++) acc[j] = 0.f;
    const float* wA = Wp + ((size_t)tA * 150 + 75) * 75 + cA;   // src half
    const float* wB = Wp + ((size_t)tB * 150 + 75) * 75 + cB;
    gemm30(hp, wA, wB, acc);
    u32* row = m32 + (size_t)(e - e_begin) * 188 + p * 15;
    if (full) {
#pragma unroll
        for (int w = 0; w < 15; w++) row[w] = pack2(acc[2 * w], acc[2 * w + 1]);
    } else {
#pragma unroll
        for (int w = 0; w < 7; w++) row[w] = pack2(acc[2 * w], acc[2 * w + 1]);
        row[7] = pack2(acc[14], 0.f);
    }
}

// ---------------- k_agg: per-node stats over chunk-relative m32 rows ----------------
__global__ __launch_bounds__(192) void k_agg(const u32* __restrict__ m32,
                                             const int* __restrict__ offs,
                                             const u32* __restrict__ baseb32,
                                             u32* __restrict__ agg32,
                                             int n0, int n1) {
    int q = threadIdx.x;
    if (q >= 188) return;
    int e_base = offs[n0];
    int o0 = 2 * q, o1 = 2 * q + 1;
    bool has1 = o1 < 375;
    int t0 = o0 / 75, c0 = o0 % 75;
    int t1 = has1 ? (o1 / 75) : 0, c1 = has1 ? (o1 % 75) : 0;
    for (int v = n0 + blockIdx.x; v < n1; v += gridDim.x) {
        int e0 = offs[v], e1 = offs[v + 1];
        float s0 = 0.f, s1 = 0.f, sq0 = 0.f, sq1 = 0.f;
        float mn0 = 3.4e38f, mn1 = 3.4e38f, mx0 = -3.4e38f, mx1 = -3.4e38f;
        for (int e = e0; e < e1; e++) {
            u32 w = m32[(size_t)(e - e_base) * 188 + q];
            float x0 = bl2f((u16)(w & 0xffffu)), x1 = bl2f((u16)(w >> 16));
            s0 += x0; sq0 = fmaf(x0, x0, sq0); mn0 = fminf(mn0, x0); mx0 = fmaxf(mx0, x0);
            s1 += x1; sq1 = fmaf(x1, x1, sq1); mn1 = fminf(mn1, x1); mx1 = fmaxf(mx1, x1);
        }
        int deg = e1 - e0;
        u32 bw = baseb32[(size_t)v * 188 + q];
        float b0 = bl2f((u16)(bw & 0xffffu)), b1 = bl2f((u16)(bw >> 16));
        float mean0, mean1, mnf0, mnf1, mxf0, mxf1, sd0, sd1;
        if (deg > 0) {
            float im = 1.f / (float)deg;
            float mm0 = s0 * im, mm1 = s1 * im;
            float v0 = fmaxf(fmaf(-mm0, mm0, sq0 * im), 0.f);
            float v1 = fmaxf(fmaf(-mm1, mm1, sq1 * im), 0.f);
            sd0 = sqrtf(v0 + 1e-5f); sd1 = sqrtf(v1 + 1e-5f);
            mean0 = b0 + mm0; mean1 = b1 + mm1;
            mnf0 = b0 + mn0;  mnf1 = b1 + mn1;
            mxf0 = b0 + mx0;  mxf1 = b1 + mx1;
        } else {
            float sde = sqrtf(1e-5f);
            mean0 = mean1 = mnf0 = mnf1 = mxf0 = mxf1 = 0.f;
            sd0 = sd1 = sde;
        }
        u32* ap = agg32 + (size_t)(v - n0) * 768;
        ap[t0 * 152 + c0] = pack2(mean0, mnf0);
        ap[t0 * 152 + 76 + c0] = pack2(mxf0, sd0);
        if (has1) {
            ap[t1 * 152 + c1] = pack2(mean1, mnf1);
            ap[t1 * 152 + 76 + c1] = pack2(mxf1, sd1);
        }
    }
}

// ---------------- k_post: thread-per-node, one tower, chunked ----------------
__global__ __launch_bounds__(256) void k_post(const float* __restrict__ hN,
                                              const int* __restrict__ offs,
                                              const u32* __restrict__ agg32,
                                              const float* __restrict__ Wq,
                                              const float* __restrict__ bq,
                                              const float* __restrict__ adl_p,
                                              float* __restrict__ tmp,
                                              int n0, int n1) {
    int t = blockIdx.x;
    int n = n0 + blockIdx.y * 256 + threadIdx.x;
    if (n >= n1) return;
    float adl = adl_p[0];
    int deg = offs[n + 1] - offs[n];
    float dc = (float)(deg > 0 ? deg : 1);
    float amp = log1pf(dc) / adl;
    float inv = 1.f / amp;
    const float* wt = Wq + (size_t)t * 975 * 15;
    float acc[15];
#pragma unroll
    for (int j = 0; j < 15; j++) acc[j] = bq[t * 15 + j];
    const float* hp = hN + (size_t)n * 80;
    for (int k = 0; k < 75; k++) {
        float in = hp[k];
        const float* wr = wt + k * 15;
#pragma unroll
        for (int j = 0; j < 15; j++) acc[j] = fmaf(in, wr[j], acc[j]);
    }
    const u32* ap = agg32 + (size_t)(n - n0) * 768 + t * 152;
    for (int c = 0; c < 75; c++) {
        u32 wA = ap[c], wB = ap[76 + c];
        float vs[4];
        vs[0] = bl2f((u16)(wA & 0xffffu)); vs[1] = bl2f((u16)(wA >> 16));
        vs[2] = bl2f((u16)(wB & 0xffffu)); vs[3] = bl2f((u16)(wB >> 16));
#pragma unroll
        for (int s4 = 0; s4 < 4; s4++) {
            float a = vs[s4], aa = a * amp, ai = a * inv;
            const float* w0 = wt + (size_t)(75 + s4 * 75 + c) * 15;
            const float* w1 = wt + (size_t)(375 + s4 * 75 + c) * 15;
            const float* w2 = wt + (size_t)(675 + s4 * 75 + c) * 15;
#pragma unroll
            for (int j = 0; j < 15; j++)
                acc[j] = fmaf(a, w0[j], fmaf(aa, w1[j], fmaf(ai, w2[j], acc[j])));
        }
    }
#pragma unroll
    for (int j = 0; j < 15; j++)
        tmp[(size_t)(t * 15 + j) * NN + n] = acc[j];
}

// ---------------- k_lin2: thread-per-node 75x75 linear + BN stats ----------------
__global__ __launch_bounds__(256) void k_lin2(const float* __restrict__ tmp,
                                              const float* __restrict__ Wl,
                                              const float* __restrict__ bl,
                                              float* __restrict__ zN,
                                              float* __restrict__ bsum,
                                              float* __restrict__ bsq) {
    int n = blockIdx.x * 256 + threadIdx.x;
    bool valid = n < NN;
    int nc = valid ? n : NN - 1;
    float acc[75];
#pragma unroll
    for (int c = 0; c < 75; c++) acc[c] = bl[c];
    for (int k = 0; k < 75; k++) {
        float in = tmp[(size_t)k * NN + nc];
        const float* wr = Wl + k * 75;
#pragma unroll
        for (int c = 0; c < 75; c++) acc[c] = fmaf(in, wr[c], acc[c]);
    }
    if (valid) {
        float4* dstp = (float4*)(zN + (size_t)n * 80);
#pragma unroll
        for (int w = 0; w < 18; w++)
            dstp[w] = make_float4(acc[4 * w], acc[4 * w + 1], acc[4 * w + 2], acc[4 * w + 3]);
        dstp[18] = make_float4(acc[72], acc[73], acc[74], 0.f);
        dstp[19] = make_float4(0.f, 0.f, 0.f, 0.f);
    }
    int lane = threadIdx.x & 63;
    for (int c0 = 0; c0 < 75; c0 += 15) {
        float s[15], ss[15];
#pragma unroll
        for (int i = 0; i < 15; i++) {
            float a = valid ? acc[c0 + i] : 0.f;
            s[i] = a; ss[i] = a * a;
        }
        for (int d = 32; d > 0; d >>= 1) {
#pragma unroll
            for (int i = 0; i < 15; i++) {
                s[i] += __shfl_down(s[i], d);
                ss[i] += __shfl_down(ss[i], d);
            }
        }
        if (lane == 0) {
#pragma unroll
            for (int i = 0; i < 15; i++) {
                atomicAdd(&bsum[c0 + i], s[i]);
                atomicAdd(&bsq[c0 + i], ss[i]);
            }
        }
    }
}

// ---------------- k_bn2: BN + ReLU node-major zN -> hN ----------------
__global__ __launch_bounds__(256) void k_bn2(const float* __restrict__ zN,
                                             const float* __restrict__ bsum,
                                             const float* __restrict__ bsq,
                                             const float* __restrict__ g,
                                             const float* __restrict__ b,
                                             float* __restrict__ hN) {
    int n = blockIdx.x * 256 + threadIdx.x;
    if (n >= NN) return;
    const float* zp = zN + (size_t)n * 80;
    float buf[80];
#pragma unroll
    for (int c = 0; c < 75; c++) {
        float mu = bsum[c] * (1.f / NN);
        float var = bsq[c] * (1.f / NN) - mu * mu;
        float sc = g[c] * rsqrtf(var + 1e-5f);
        float v = (zp[c] - mu) * sc + b[c];
        buf[c] = v > 0.f ? v : 0.f;
    }
#pragma unroll
    for (int c = 75; c < 80; c++) buf[c] = 0.f;
    float4* dstp = (float4*)(hN + (size_t)n * 80);
#pragma unroll
    for (int w = 0; w < 20; w++)
        dstp[w] = make_float4(buf[4 * w], buf[4 * w + 1], buf[4 * w + 2], buf[4 * w + 3]);
}

// ---------------- MLP head ----------------
__global__ __launch_bounds__(256) void k_mlp1(const float* __restrict__ hN,
                                              const float* __restrict__ alpha,
                                              const int* __restrict__ batch,
                                              const float* __restrict__ w1,
                                              const float* __restrict__ b1,
                                              float* __restrict__ t1) {
    int n = blockIdx.x * 256 + threadIdx.x;
    if (n >= NN) return;
    float acc[50];
#pragma unroll
    for (int j = 0; j < 50; j++) acc[j] = b1[j];
    const float* hp = hN + (size_t)n * 80;
    for (int k = 0; k < 75; k++) {
        float in = hp[k];
        const float* wr = w1 + k * 50;
#pragma unroll
        for (int j = 0; j < 50; j++) acc[j] = fmaf(in, wr[j], acc[j]);
    }
    float a = alpha[batch[n]];
    const float* wr = w1 + 75 * 50;
#pragma unroll
    for (int j = 0; j < 50; j++) {
        float v = fmaf(a, wr[j], acc[j]);
        t1[(size_t)j * NN + n] = v > 0.f ? v : 0.f;
    }
}

__global__ void k_mlp2(const float* __restrict__ t1, const float* __restrict__ w2,
                       const float* __restrict__ b2, const float* __restrict__ w3,
                       const float* __restrict__ b3, const float* __restrict__ noise,
                       const float* __restrict__ x, float* __restrict__ out) {
    int n = blockIdx.x * 256 + threadIdx.x;
    if (n >= NN) return;
    float tr[50];
#pragma unroll
    for (int k = 0; k < 50; k++) tr[k] = t1[(size_t)k * NN + n];
    float y = b3[0];
#pragma unroll
    for (int k2 = 0; k2 < 25; k2++) {
        float acc = b2[k2];
#pragma unroll
        for (int k = 0; k < 50; k++) acc = fmaf(tr[k], w2[k * 25 + k2], acc);
        acc = acc > 0.f ? acc : 0.f;
        y = fmaf(acc, w3[k2], y);
    }
    float z = y + noise[n];
    float s = 1.f / (1.f + expf(-z));
    out[n] = s;
    out[NN + n] = x[2 * n];
}

extern "C" void kernel_launch(void* const* d_in, const int* in_sizes, int n_in,
                              void* d_out, int out_size, void* d_ws, size_t ws_size,
                              hipStream_t stream) {
    const float* x      = (const float*)d_in[0];
    const float* alpha  = (const float*)d_in[1];
    const int*   ei     = (const int*)d_in[2];
    const int*   batch  = (const int*)d_in[3];
    const float* noise  = (const float*)d_in[4];
    const float* adl    = (const float*)d_in[5];
    const float* pre_w  = (const float*)d_in[6];
    const float* pre_b  = (const float*)d_in[7];
    const float* W_pre  = (const float*)d_in[8];
    const float* b_pre  = (const float*)d_in[9];
    const float* W_post = (const float*)d_in[10];
    const float* b_post = (const float*)d_in[11];
    const float* W_lin  = (const float*)d_in[12];
    const float* b_lin  = (const float*)d_in[13];
    const float* bn_g   = (const float*)d_in[14];
    const float* bn_b   = (const float*)d_in[15];
    const float* mw1    = (const float*)d_in[16];
    const float* mb1    = (const float*)d_in[17];
    const float* mw2    = (const float*)d_in[18];
    const float* mb2    = (const float*)d_in[19];
    const float* mw3    = (const float*)d_in[20];
    const float* mb3    = (const float*)d_in[21];
    (void)in_sizes; (void)n_in; (void)out_size; (void)ws_size;

    char* ws = (char*)d_ws;
    size_t off = 0;
    auto alloc = [&](size_t bytes) -> char* {
        char* p = ws + off;
        off += (bytes + 255) & ~((size_t)255);
        return p;
    };
    float* hN     = (float*)alloc((size_t)NN * 80 * 4);
    float* zN     = (float*)alloc((size_t)NN * 80 * 4);
    float* tmp    = (float*)alloc((size_t)75 * NN * 4);
    u32*   agg32  = (u32*)alloc((size_t)NCH * 768 * 4);
    u32*   baseb32= (u32*)alloc((size_t)NN * 188 * 4);
    u32*   m32    = (u32*)alloc((size_t)ECH * 188 * 4);
    int*   cnt    = (int*)alloc((size_t)NN * 4);
    int*   offs   = (int*)alloc((size_t)(NN + 1) * 4);
    int*   fill   = (int*)alloc((size_t)NN * 4);
    int*   csr    = (int*)alloc((size_t)EE * 4);
    float* bnsum  = (float*)alloc(4 * 75 * 4);
    float* bnsq   = (float*)alloc(4 * 75 * 4);

    hipMemsetAsync(cnt, 0, (size_t)NN * 4, stream);
    hipMemsetAsync(fill, 0, (size_t)NN * 4, stream);
    hipMemsetAsync(bnsum, 0, 4 * 75 * 4, stream);
    hipMemsetAsync(bnsq, 0, 4 * 75 * 4, stream);

    const int* src = ei;
    const int* dst = ei + EE;
    int eb = (EE + 255) / 256;
    int nb = (NN + 255) / 256;
    int cb = (NCH + 255) / 256;
    int mb = (ECH + 255) / 256;

    k_count<<<eb, 256, 0, stream>>>(dst, cnt);
    k_scan<<<1, 1024, 0, stream>>>(cnt, offs);
    k_scatter<<<eb, 256, 0, stream>>>(src, dst, offs, fill, csr);
    k_pre<<<nb, 256, 0, stream>>>(x, pre_w, pre_b, hN);

    for (int l = 0; l < 4; l++) {
        const float* Wp  = W_pre + (size_t)l * 5 * 150 * 75;
        const float* bp  = b_pre + l * 375;
        const float* Wq  = W_post + (size_t)l * 5 * 975 * 15;
        const float* bq  = b_post + l * 75;
        const float* Wl  = W_lin + l * 75 * 75;
        const float* blp = b_lin + l * 75;
        k_base<<<dim3(nb, 13), 256, 0, stream>>>(hN, Wp, bp, baseb32);
        for (int ch = 0; ch < 2; ch++) {
            int n0 = ch * NCH, n1 = n0 + NCH;
            k_msg<<<dim3(mb, 13), 256, 0, stream>>>(hN, csr, Wp, m32, offs, n0, n1);
            k_agg<<<2048, 192, 0, stream>>>(m32, offs, baseb32, agg32, n0, n1);
            k_post<<<dim3(5, cb), 256, 0, stream>>>(hN, offs, agg32, Wq, bq, adl, tmp, n0, n1);
        }
        k_lin2<<<nb, 256, 0, stream>>>(tmp, Wl, blp, zN, bnsum + l * 75, bnsq + l * 75);
        k_bn2<<<nb, 256, 0, stream>>>(zN, bnsum + l * 75, bnsq + l * 75,
                                      bn_g + l * 75, bn_b + l * 75, hN);
    }

    float* t1 = tmp;
    k_mlp1<<<nb, 256, 0, stream>>>(hN, alpha, batch, mw1, mb1, t1);
    k_mlp2<<<nb, 256, 0, stream>>>(t1, mw2, mb2, mw3, mb3, noise, x, (float*)d_out);
}

// Round 7
// 3006.684 us; speedup vs baseline: 3.6305x; 1.2240x over previous
//
#include <hip/hip_runtime.h>
#include <hip/hip_bf16.h>
#include <cstdint>
#include <cstddef>

#define NN 30000
#define EE 150000
#define NCH 15000   // nodes per chunk (2 chunks)
#define ECH 80000   // m32 rows budget per chunk (~75000 expected)

using u16 = unsigned short;
using u32 = unsigned int;

__device__ __forceinline__ float bl2f(u16 u) { return __uint_as_float(((u32)u) << 16); }
__device__ __forceinline__ u16 f2bl(float f) {
    u32 x = __float_as_uint(f);
    return (u16)((x + 0x7fffu + ((x >> 16) & 1u)) >> 16);
}
__device__ __forceinline__ u32 pack2(float a, float b) {
    return (u32)f2bl(a) | ((u32)f2bl(b) << 16);
}

// ---------------- CSR build ----------------
__global__ void k_count(const int* __restrict__ dst, int* __restrict__ cnt) {
    int e = blockIdx.x * 256 + threadIdx.x;
    if (e < EE) atomicAdd(&cnt[dst[e]], 1);
}

__global__ void k_scan(const int* __restrict__ cnt, int* __restrict__ offs) {
    __shared__ int ss[1024];
    int t = threadIdx.x;
    int base = t * 30;
    int s = 0;
    for (int i = 0; i < 30; i++) { int idx = base + i; if (idx < NN) s += cnt[idx]; }
    ss[t] = s; __syncthreads();
    for (int off = 1; off < 1024; off <<= 1) {
        int v = (t >= off) ? ss[t - off] : 0;
        __syncthreads();
        ss[t] += v;
        __syncthreads();
    }
    int run = (t == 0) ? 0 : ss[t - 1];
    for (int i = 0; i < 30; i++) {
        int idx = base + i;
        if (idx < NN) { offs[idx] = run; run += cnt[idx]; }
    }
    if (t == 1023) offs[NN] = run;
}

__global__ void k_scatter(const int* __restrict__ src, const int* __restrict__ dst,
                          const int* __restrict__ offs, int* __restrict__ fill,
                          int* __restrict__ csr) {
    int e = blockIdx.x * 256 + threadIdx.x;
    if (e < EE) {
        int d = dst[e];
        int p = offs[d] + atomicAdd(&fill[d], 1);
        csr[p] = src[e];
    }
}

// ---------------- pre linear: hN[n][80] ----------------
__global__ void k_pre(const float* __restrict__ x, const float* __restrict__ pw,
                      const float* __restrict__ pb, float* __restrict__ hN) {
    int n = blockIdx.x * 256 + threadIdx.x;
    if (n >= NN) return;
    float x0 = x[2 * n], x1 = x[2 * n + 1];
    float buf[80];
#pragma unroll
    for (int c = 0; c < 80; c++)
        buf[c] = (c < 75) ? fmaf(x0, pw[c], fmaf(x1, pw[75 + c], pb[c])) : 0.f;
    float4* dstp = (float4*)(hN + (size_t)n * 80);
#pragma unroll
    for (int w = 0; w < 20; w++)
        dstp[w] = make_float4(buf[4 * w], buf[4 * w + 1], buf[4 * w + 2], buf[4 * w + 3]);
}

// ---- shared inner: 30 outputs (two 15-chunks) of h(75) x Wp, wave-uniform weights ----
__device__ __forceinline__ void gemm30(const float* __restrict__ hp,
                                       const float* __restrict__ wA,
                                       const float* __restrict__ wB,
                                       float* acc) {
    for (int fq = 0; fq < 18; fq++) {
        float4 h4 = *(const float4*)(hp + fq * 4);
        const float* ra = wA + fq * 300;
        const float* rb = wB + fq * 300;
#pragma unroll
        for (int k = 0; k < 4; k++) {
            float in = (k == 0) ? h4.x : (k == 1) ? h4.y : (k == 2) ? h4.z : h4.w;
#pragma unroll
            for (int j = 0; j < 15; j++) acc[j] = fmaf(in, ra[k * 75 + j], acc[j]);
#pragma unroll
            for (int j = 0; j < 15; j++) acc[15 + j] = fmaf(in, rb[k * 75 + j], acc[15 + j]);
        }
    }
#pragma unroll
    for (int f = 72; f < 75; f++) {
        float in = hp[f];
#pragma unroll
        for (int j = 0; j < 15; j++) acc[j] = fmaf(in, wA[f * 75 + j], acc[j]);
#pragma unroll
        for (int j = 0; j < 15; j++) acc[15 + j] = fmaf(in, wB[f * 75 + j], acc[15 + j]);
    }
}

// ---------------- k_base: thread-per-node x 13 pair-chunks -> baseb32[n][188] --------
__global__ __launch_bounds__(256) void k_base(const float* __restrict__ hN,
                                              const float* __restrict__ Wp,
                                              const float* __restrict__ bp,
                                              u32* __restrict__ baseb32) {
    int n = blockIdx.x * 256 + threadIdx.x;
    int p = blockIdx.y;               // 0..12, block-uniform
    if (n >= NN) return;
    const float* hp = hN + (size_t)n * 80;
    int o0 = p * 30;
    int cg = p * 2;
    int tA = cg / 5, cA = (cg % 5) * 15;
    bool full = p < 12;
    int cg1 = full ? cg + 1 : cg;
    int tB = cg1 / 5, cB = (cg1 % 5) * 15;
    float acc[30];
#pragma unroll
    for (int j = 0; j < 15; j++) acc[j] = bp[o0 + j];
#pragma unroll
    for (int j = 0; j < 15; j++) acc[15 + j] = full ? bp[o0 + 15 + j] : 0.f;
    const float* wA = Wp + (size_t)tA * 150 * 75 + cA;
    const float* wB = Wp + (size_t)tB * 150 * 75 + cB;
    gemm30(hp, wA, wB, acc);
    u32* row = baseb32 + (size_t)n * 188 + p * 15;
    if (full) {
#pragma unroll
        for (int w = 0; w < 15; w++) row[w] = pack2(acc[2 * w], acc[2 * w + 1]);
    } else {
#pragma unroll
        for (int w = 0; w < 7; w++) row[w] = pack2(acc[2 * w], acc[2 * w + 1]);
        row[7] = pack2(acc[14], 0.f);
    }
}

// ---------------- k_msg: thread-per-edge x 13 pair-chunks -> m32[row][188] ----------
__global__ __launch_bounds__(256) void k_msg(const float* __restrict__ hN,
                                             const int* __restrict__ csr,
                                             const float* __restrict__ Wp,
                                             u32* __restrict__ m32,
                                             const int* __restrict__ offs,
                                             int n0, int n1) {
    int e_begin = offs[n0], e_end = offs[n1];
    int e = e_begin + blockIdx.x * 256 + threadIdx.x;
    if (e >= e_end) return;
    int p = blockIdx.y;               // 0..12, block-uniform
    int su = csr[e];
    const float* hp = hN + (size_t)su * 80;
    int cg = p * 2;
    int tA = cg / 5, cA = (cg % 5) * 15;
    bool full = p < 12;
    int cg1 = full ? cg + 1 : cg;
    int tB = cg1 / 5, cB = (cg1 % 5) * 15;
    float acc[30];
#pragma unroll
    for (int j = 0; j < 30; j++) acc[j] = 0.f;
    const float* wA = Wp + ((size_t)tA * 150 + 75) * 75 + cA;   // src half
    const float* wB = Wp + ((size_t)tB * 150 + 75) * 75 + cB;
    gemm30(hp, wA, wB, acc);
    u32* row = m32 + (size_t)(e - e_begin) * 188 + p * 15;
    if (full) {
#pragma unroll
        for (int w = 0; w < 15; w++) row[w] = pack2(acc[2 * w], acc[2 * w + 1]);
    } else {
#pragma unroll
        for (int w = 0; w < 7; w++) row[w] = pack2(acc[2 * w], acc[2 * w + 1]);
        row[7] = pack2(acc[14], 0.f);
    }
}

// ---------------- k_agg: per-node stats over chunk-relative m32 rows ----------------
__global__ __launch_bounds__(192) void k_agg(const u32* __restrict__ m32,
                                             const int* __restrict__ offs,
                                             const u32* __restrict__ baseb32,
                                             u32* __restrict__ agg32,
                                             int n0, int n1) {
    int q = threadIdx.x;
    if (q >= 188) return;
    int e_base = offs[n0];
    int o0 = 2 * q, o1 = 2 * q + 1;
    bool has1 = o1 < 375;
    int t0 = o0 / 75, c0 = o0 % 75;
    int t1 = has1 ? (o1 / 75) : 0, c1 = has1 ? (o1 % 75) : 0;
    for (int v = n0 + blockIdx.x; v < n1; v += gridDim.x) {
        int e0 = offs[v], e1 = offs[v + 1];
        float s0 = 0.f, s1 = 0.f, sq0 = 0.f, sq1 = 0.f;
        float mn0 = 3.4e38f, mn1 = 3.4e38f, mx0 = -3.4e38f, mx1 = -3.4e38f;
        for (int e = e0; e < e1; e++) {
            u32 w = m32[(size_t)(e - e_base) * 188 + q];
            float x0 = bl2f((u16)(w & 0xffffu)), x1 = bl2f((u16)(w >> 16));
            s0 += x0; sq0 = fmaf(x0, x0, sq0); mn0 = fminf(mn0, x0); mx0 = fmaxf(mx0, x0);
            s1 += x1; sq1 = fmaf(x1, x1, sq1); mn1 = fminf(mn1, x1); mx1 = fmaxf(mx1, x1);
        }
        int deg = e1 - e0;
        u32 bw = baseb32[(size_t)v * 188 + q];
        float b0 = bl2f((u16)(bw & 0xffffu)), b1 = bl2f((u16)(bw >> 16));
        float mean0, mean1, mnf0, mnf1, mxf0, mxf1, sd0, sd1;
        if (deg > 0) {
            float im = 1.f / (float)deg;
            float mm0 = s0 * im, mm1 = s1 * im;
            float v0 = fmaxf(fmaf(-mm0, mm0, sq0 * im), 0.f);
            float v1 = fmaxf(fmaf(-mm1, mm1, sq1 * im), 0.f);
            sd0 = sqrtf(v0 + 1e-5f); sd1 = sqrtf(v1 + 1e-5f);
            mean0 = b0 + mm0; mean1 = b1 + mm1;
            mnf0 = b0 + mn0;  mnf1 = b1 + mn1;
            mxf0 = b0 + mx0;  mxf1 = b1 + mx1;
        } else {
            float sde = sqrtf(1e-5f);
            mean0 = mean1 = mnf0 = mnf1 = mxf0 = mxf1 = 0.f;
            sd0 = sd1 = sde;
        }
        u32* ap = agg32 + (size_t)(v - n0) * 768;
        ap[t0 * 152 + c0] = pack2(mean0, mnf0);
        ap[t0 * 152 + 76 + c0] = pack2(mxf0, sd0);
        if (has1) {
            ap[t1 * 152 + c1] = pack2(mean1, mnf1);
            ap[t1 * 152 + 76 + c1] = pack2(mxf1, sd1);
        }
    }
}

// ---------------- k_post: thread-per-node, one tower, vectorized loads ----------------
__global__ __launch_bounds__(256) void k_post(const float* __restrict__ hN,
                                              const int* __restrict__ offs,
                                              const u32* __restrict__ agg32,
                                              const float* __restrict__ Wq,
                                              const float* __restrict__ bq,
                                              const float* __restrict__ adl_p,
                                              float* __restrict__ tmp,
                                              int n0, int n1) {
    int t = blockIdx.x;
    int n = n0 + blockIdx.y * 256 + threadIdx.x;
    if (n >= n1) return;
    float adl = adl_p[0];
    int deg = offs[n + 1] - offs[n];
    float dc = (float)(deg > 0 ? deg : 1);
    float amp = log1pf(dc) / adl;
    float inv = 1.f / amp;
    const float* wt = Wq + (size_t)t * 975 * 15;
    float acc[15];
#pragma unroll
    for (int j = 0; j < 15; j++) acc[j] = bq[t * 15 + j];
    const float4* hp4 = (const float4*)(hN + (size_t)n * 80);
#pragma unroll
    for (int fq = 0; fq < 19; fq++) {
        float4 h4 = hp4[fq];
#pragma unroll
        for (int k2 = 0; k2 < 4; k2++) {
            int kk = fq * 4 + k2;
            if (kk < 75) {
                float in = (k2 == 0) ? h4.x : (k2 == 1) ? h4.y : (k2 == 2) ? h4.z : h4.w;
                const float* wr = wt + kk * 15;
#pragma unroll
                for (int j = 0; j < 15; j++) acc[j] = fmaf(in, wr[j], acc[j]);
            }
        }
    }
    const uint4* apA = (const uint4*)(agg32 + (size_t)(n - n0) * 768 + t * 152);
    const uint4* apB = (const uint4*)(agg32 + (size_t)(n - n0) * 768 + t * 152 + 76);
    for (int cq = 0; cq < 19; cq++) {
        uint4 A = apA[cq];
        uint4 B = apB[cq];
#pragma unroll
        for (int i = 0; i < 4; i++) {
            int c = cq * 4 + i;
            if (c < 75) {
                u32 wA = (i == 0) ? A.x : (i == 1) ? A.y : (i == 2) ? A.z : A.w;
                u32 wB = (i == 0) ? B.x : (i == 1) ? B.y : (i == 2) ? B.z : B.w;
                float vs[4];
                vs[0] = bl2f((u16)(wA & 0xffffu)); vs[1] = bl2f((u16)(wA >> 16));
                vs[2] = bl2f((u16)(wB & 0xffffu)); vs[3] = bl2f((u16)(wB >> 16));
#pragma unroll
                for (int s4 = 0; s4 < 4; s4++) {
                    float a = vs[s4], aa = a * amp, ai = a * inv;
                    const float* w0 = wt + (size_t)(75 + s4 * 75 + c) * 15;
                    const float* w1 = wt + (size_t)(375 + s4 * 75 + c) * 15;
                    const float* w2 = wt + (size_t)(675 + s4 * 75 + c) * 15;
#pragma unroll
                    for (int j = 0; j < 15; j++)
                        acc[j] = fmaf(a, w0[j], fmaf(aa, w1[j], fmaf(ai, w2[j], acc[j])));
                }
            }
        }
    }
#pragma unroll
    for (int j = 0; j < 15; j++)
        tmp[(size_t)(t * 15 + j) * NN + n] = acc[j];
}

// ---------------- k_lin2: (nodes x 5 chunks), LDS-staged Wl slice, zF out ----------
__global__ __launch_bounds__(256) void k_lin2(const float* __restrict__ tmp,
                                              const float* __restrict__ Wl,
                                              const float* __restrict__ bl,
                                              float* __restrict__ zF,
                                              float* __restrict__ bsum,
                                              float* __restrict__ bsq) {
    __shared__ __align__(16) float wl[75][16];
    __shared__ float red1[4][15], red2[4][15];
    int p = blockIdx.y;               // output chunk 0..4 (15 channels)
    for (int idx = threadIdx.x; idx < 75 * 15; idx += 256) {
        int k = idx / 15, j = idx % 15;
        wl[k][j] = Wl[k * 75 + p * 15 + j];
    }
    __syncthreads();
    int n = blockIdx.x * 256 + threadIdx.x;
    bool valid = n < NN;
    int nc = valid ? n : NN - 1;
    float acc[15];
#pragma unroll
    for (int j = 0; j < 15; j++) acc[j] = bl[p * 15 + j];
    for (int k = 0; k < 75; k++) {
        float in = tmp[(size_t)k * NN + nc];
        float4 w0 = *(const float4*)&wl[k][0];
        float4 w1 = *(const float4*)&wl[k][4];
        float4 w2 = *(const float4*)&wl[k][8];
        float4 w3 = *(const float4*)&wl[k][12];
        acc[0] = fmaf(in, w0.x, acc[0]);  acc[1] = fmaf(in, w0.y, acc[1]);
        acc[2] = fmaf(in, w0.z, acc[2]);  acc[3] = fmaf(in, w0.w, acc[3]);
        acc[4] = fmaf(in, w1.x, acc[4]);  acc[5] = fmaf(in, w1.y, acc[5]);
        acc[6] = fmaf(in, w1.z, acc[6]);  acc[7] = fmaf(in, w1.w, acc[7]);
        acc[8] = fmaf(in, w2.x, acc[8]);  acc[9] = fmaf(in, w2.y, acc[9]);
        acc[10] = fmaf(in, w2.z, acc[10]); acc[11] = fmaf(in, w2.w, acc[11]);
        acc[12] = fmaf(in, w3.x, acc[12]); acc[13] = fmaf(in, w3.y, acc[13]);
        acc[14] = fmaf(in, w3.z, acc[14]);
    }
    if (valid) {
#pragma unroll
        for (int j = 0; j < 15; j++)
            zF[(size_t)(p * 15 + j) * NN + n] = acc[j];
    }
    // BN stats: wave shuffle reduce -> LDS -> 30 atomics/block
    float s[15], ss[15];
#pragma unroll
    for (int i = 0; i < 15; i++) {
        float a = valid ? acc[i] : 0.f;
        s[i] = a; ss[i] = a * a;
    }
    for (int d = 32; d > 0; d >>= 1) {
#pragma unroll
        for (int i = 0; i < 15; i++) {
            s[i] += __shfl_down(s[i], d);
            ss[i] += __shfl_down(ss[i], d);
        }
    }
    int wave = threadIdx.x >> 6, lane = threadIdx.x & 63;
    if (lane == 0) {
#pragma unroll
        for (int i = 0; i < 15; i++) { red1[wave][i] = s[i]; red2[wave][i] = ss[i]; }
    }
    __syncthreads();
    if (threadIdx.x < 15) {
        int i = threadIdx.x;
        float a = red1[0][i] + red1[1][i] + red1[2][i] + red1[3][i];
        float b = red2[0][i] + red2[1][i] + red2[2][i] + red2[3][i];
        atomicAdd(&bsum[p * 15 + i], a);
        atomicAdd(&bsq[p * 15 + i], b);
    }
}

// ---------------- k_bn2: BN + ReLU, zF (feature-major) -> hN (node-major) ----------
__global__ __launch_bounds__(256) void k_bn2(const float* __restrict__ zF,
                                             const float* __restrict__ bsum,
                                             const float* __restrict__ bsq,
                                             const float* __restrict__ g,
                                             const float* __restrict__ b,
                                             float* __restrict__ hN) {
    int n = blockIdx.x * 256 + threadIdx.x;
    if (n >= NN) return;
    float buf[80];
    for (int c = 0; c < 75; c++) {
        float mu = bsum[c] * (1.f / NN);
        float var = bsq[c] * (1.f / NN) - mu * mu;
        float sc = g[c] * rsqrtf(var + 1e-5f);
        float v = (zF[(size_t)c * NN + n] - mu) * sc + b[c];
        buf[c] = v > 0.f ? v : 0.f;
    }
#pragma unroll
    for (int c = 75; c < 80; c++) buf[c] = 0.f;
    float4* dstp = (float4*)(hN + (size_t)n * 80);
#pragma unroll
    for (int w = 0; w < 20; w++)
        dstp[w] = make_float4(buf[4 * w], buf[4 * w + 1], buf[4 * w + 2], buf[4 * w + 3]);
}

// ---------------- MLP head ----------------
__global__ __launch_bounds__(256) void k_mlp1(const float* __restrict__ hN,
                                              const float* __restrict__ alpha,
                                              const int* __restrict__ batch,
                                              const float* __restrict__ w1,
                                              const float* __restrict__ b1,
                                              float* __restrict__ t1) {
    int n = blockIdx.x * 256 + threadIdx.x;
    if (n >= NN) return;
    float acc[50];
#pragma unroll
    for (int j = 0; j < 50; j++) acc[j] = b1[j];
    const float4* hp4 = (const float4*)(hN + (size_t)n * 80);
#pragma unroll
    for (int fq = 0; fq < 19; fq++) {
        float4 h4 = hp4[fq];
#pragma unroll
        for (int k2 = 0; k2 < 4; k2++) {
            int kk = fq * 4 + k2;
            if (kk < 75) {
                float in = (k2 == 0) ? h4.x : (k2 == 1) ? h4.y : (k2 == 2) ? h4.z : h4.w;
                const float* wr = w1 + kk * 50;
#pragma unroll
                for (int j = 0; j < 50; j++) acc[j] = fmaf(in, wr[j], acc[j]);
            }
        }
    }
    float a = alpha[batch[n]];
    const float* wr = w1 + 75 * 50;
#pragma unroll
    for (int j = 0; j < 50; j++) {
        float v = fmaf(a, wr[j], acc[j]);
        t1[(size_t)j * NN + n] = v > 0.f ? v : 0.f;
    }
}

__global__ void k_mlp2(const float* __restrict__ t1, const float* __restrict__ w2,
                       const float* __restrict__ b2, const float* __restrict__ w3,
                       const float* __restrict__ b3, const float* __restrict__ noise,
                       const float* __restrict__ x, float* __restrict__ out) {
    int n = blockIdx.x * 256 + threadIdx.x;
    if (n >= NN) return;
    float tr[50];
#pragma unroll
    for (int k = 0; k < 50; k++) tr[k] = t1[(size_t)k * NN + n];
    float y = b3[0];
#pragma unroll
    for (int k2 = 0; k2 < 25; k2++) {
        float acc = b2[k2];
#pragma unroll
        for (int k = 0; k < 50; k++) acc = fmaf(tr[k], w2[k * 25 + k2], acc);
        acc = acc > 0.f ? acc : 0.f;
        y = fmaf(acc, w3[k2], y);
    }
    float z = y + noise[n];
    float s = 1.f / (1.f + expf(-z));
    out[n] = s;
    out[NN + n] = x[2 * n];
}

extern "C" void kernel_launch(void* const* d_in, const int* in_sizes, int n_in,
                              void* d_out, int out_size, void* d_ws, size_t ws_size,
                              hipStream_t stream) {
    const float* x      = (const float*)d_in[0];
    const float* alpha  = (const float*)d_in[1];
    const int*   ei     = (const int*)d_in[2];
    const int*   batch  = (const int*)d_in[3];
    const float* noise  = (const float*)d_in[4];
    const float* adl    = (const float*)d_in[5];
    const float* pre_w  = (const float*)d_in[6];
    const float* pre_b  = (const float*)d_in[7];
    const float* W_pre  = (const float*)d_in[8];
    const float* b_pre  = (const float*)d_in[9];
    const float* W_post = (const float*)d_in[10];
    const float* b_post = (const float*)d_in[11];
    const float* W_lin  = (const float*)d_in[12];
    const float* b_lin  = (const float*)d_in[13];
    const float* bn_g   = (const float*)d_in[14];
    const float* bn_b   = (const float*)d_in[15];
    const float* mw1    = (const float*)d_in[16];
    const float* mb1    = (const float*)d_in[17];
    const float* mw2    = (const float*)d_in[18];
    const float* mb2    = (const float*)d_in[19];
    const float* mw3    = (const float*)d_in[20];
    const float* mb3    = (const float*)d_in[21];
    (void)in_sizes; (void)n_in; (void)out_size; (void)ws_size;

    char* ws = (char*)d_ws;
    size_t off = 0;
    auto alloc = [&](size_t bytes) -> char* {
        char* p = ws + off;
        off += (bytes + 255) & ~((size_t)255);
        return p;
    };
    float* hN     = (float*)alloc((size_t)NN * 80 * 4);
    float* zF     = (float*)alloc((size_t)75 * NN * 4);
    float* tmp    = (float*)alloc((size_t)75 * NN * 4);
    u32*   agg32  = (u32*)alloc((size_t)NCH * 768 * 4);
    u32*   baseb32= (u32*)alloc((size_t)NN * 188 * 4);
    u32*   m32    = (u32*)alloc((size_t)ECH * 188 * 4);
    int*   cnt    = (int*)alloc((size_t)NN * 4);
    int*   offs   = (int*)alloc((size_t)(NN + 1) * 4);
    int*   fill   = (int*)alloc((size_t)NN * 4);
    int*   csr    = (int*)alloc((size_t)EE * 4);
    float* bnsum  = (float*)alloc(4 * 75 * 4);
    float* bnsq   = (float*)alloc(4 * 75 * 4);

    hipMemsetAsync(cnt, 0, (size_t)NN * 4, stream);
    hipMemsetAsync(fill, 0, (size_t)NN * 4, stream);
    hipMemsetAsync(bnsum, 0, 4 * 75 * 4, stream);
    hipMemsetAsync(bnsq, 0, 4 * 75 * 4, stream);

    const int* src = ei;
    const int* dst = ei + EE;
    int eb = (EE + 255) / 256;
    int nb = (NN + 255) / 256;
    int cb = (NCH + 255) / 256;
    int mb = (ECH + 255) / 256;

    k_count<<<eb, 256, 0, stream>>>(dst, cnt);
    k_scan<<<1, 1024, 0, stream>>>(cnt, offs);
    k_scatter<<<eb, 256, 0, stream>>>(src, dst, offs, fill, csr);
    k_pre<<<nb, 256, 0, stream>>>(x, pre_w, pre_b, hN);

    for (int l = 0; l < 4; l++) {
        const float* Wp  = W_pre + (size_t)l * 5 * 150 * 75;
        const float* bp  = b_pre + l * 375;
        const float* Wq  = W_post + (size_t)l * 5 * 975 * 15;
        const float* bq  = b_post + l * 75;
        const float* Wl  = W_lin + l * 75 * 75;
        const float* blp = b_lin + l * 75;
        k_base<<<dim3(nb, 13), 256, 0, stream>>>(hN, Wp, bp, baseb32);
        for (int ch = 0; ch < 2; ch++) {
            int n0 = ch * NCH, n1 = n0 + NCH;
            k_msg<<<dim3(mb, 13), 256, 0, stream>>>(hN, csr, Wp, m32, offs, n0, n1);
            k_agg<<<2048, 192, 0, stream>>>(m32, offs, baseb32, agg32, n0, n1);
            k_post<<<dim3(5, cb), 256, 0, stream>>>(hN, offs, agg32, Wq, bq, adl, tmp, n0, n1);
        }
        k_lin2<<<dim3(nb, 5), 256, 0, stream>>>(tmp, Wl, blp, zF, bnsum + l * 75, bnsq + l * 75);
        k_bn2<<<nb, 256, 0, stream>>>(zF, bnsum + l * 75, bnsq + l * 75,
                                      bn_g + l * 75, bn_b + l * 75, hN);
    }

    float* t1 = tmp;
    k_mlp1<<<nb, 256, 0, stream>>>(hN, alpha, batch, mw1, mb1, t1);
    k_mlp2<<<nb, 256, 0, stream>>>(t1, mw2, mb2, mw3, mb3, noise, x, (float*)d_out);
}

// Round 8
// 2793.074 us; speedup vs baseline: 3.9081x; 1.0765x over previous
//
#include <hip/hip_runtime.h>
#include <hip/hip_bf16.h>
#include <cstdint>
#include <cstddef>

#define NN 30000
#define EE 150000
#define NCH 15000   // nodes per chunk (2 chunks)
#define ECH 80000   // m32 rows budget per chunk (~75000 expected)

using u16 = unsigned short;
using u32 = unsigned int;

__device__ __forceinline__ float bl2f(u16 u) { return __uint_as_float(((u32)u) << 16); }
__device__ __forceinline__ u16 f2bl(float f) {
    u32 x = __float_as_uint(f);
    return (u16)((x + 0x7fffu + ((x >> 16) & 1u)) >> 16);
}
__device__ __forceinline__ u32 pack2(float a, float b) {
    return (u32)f2bl(a) | ((u32)f2bl(b) << 16);
}

// ---------------- CSR build ----------------
__global__ void k_count(const int* __restrict__ dst, int* __restrict__ cnt) {
    int e = blockIdx.x * 256 + threadIdx.x;
    if (e < EE) atomicAdd(&cnt[dst[e]], 1);
}

__global__ void k_scan(const int* __restrict__ cnt, int* __restrict__ offs) {
    __shared__ int ss[1024];
    int t = threadIdx.x;
    int base = t * 30;
    int s = 0;
    for (int i = 0; i < 30; i++) { int idx = base + i; if (idx < NN) s += cnt[idx]; }
    ss[t] = s; __syncthreads();
    for (int off = 1; off < 1024; off <<= 1) {
        int v = (t >= off) ? ss[t - off] : 0;
        __syncthreads();
        ss[t] += v;
        __syncthreads();
    }
    int run = (t == 0) ? 0 : ss[t - 1];
    for (int i = 0; i < 30; i++) {
        int idx = base + i;
        if (idx < NN) { offs[idx] = run; run += cnt[idx]; }
    }
    if (t == 1023) offs[NN] = run;
}

__global__ void k_scatter(const int* __restrict__ src, const int* __restrict__ dst,
                          const int* __restrict__ offs, int* __restrict__ fill,
                          int* __restrict__ csr) {
    int e = blockIdx.x * 256 + threadIdx.x;
    if (e < EE) {
        int d = dst[e];
        int p = offs[d] + atomicAdd(&fill[d], 1);
        csr[p] = src[e];
    }
}

// ---------------- k_wqt: transpose agg-part of W_post into c-major layout --------
// wqt[lt][c][s4][grp][j], lt = l*5+t : 20*75*4*3*15 = 270000 floats
__global__ void k_wqt(const float* __restrict__ W_post, float* __restrict__ wqt) {
    int idx = blockIdx.x * 256 + threadIdx.x;
    if (idx >= 270000) return;
    int j = idx % 15;
    int grp = (idx / 15) % 3;
    int s4 = (idx / 45) % 4;
    int c = (idx / 180) % 75;
    int lt = idx / 13500;
    wqt[idx] = W_post[(size_t)lt * 975 * 15 + (size_t)(75 + grp * 300 + s4 * 75 + c) * 15 + j];
}

// ---------------- pre linear: hN[n][80] ----------------
__global__ void k_pre(const float* __restrict__ x, const float* __restrict__ pw,
                      const float* __restrict__ pb, float* __restrict__ hN) {
    int n = blockIdx.x * 256 + threadIdx.x;
    if (n >= NN) return;
    float x0 = x[2 * n], x1 = x[2 * n + 1];
    float buf[80];
#pragma unroll
    for (int c = 0; c < 80; c++)
        buf[c] = (c < 75) ? fmaf(x0, pw[c], fmaf(x1, pw[75 + c], pb[c])) : 0.f;
    float4* dstp = (float4*)(hN + (size_t)n * 80);
#pragma unroll
    for (int w = 0; w < 20; w++)
        dstp[w] = make_float4(buf[4 * w], buf[4 * w + 1], buf[4 * w + 2], buf[4 * w + 3]);
}

// ---- shared inner: 30 outputs (two 15-chunks) of h(75) x Wp, wave-uniform weights ----
__device__ __forceinline__ void gemm30(const float* __restrict__ hp,
                                       const float* __restrict__ wA,
                                       const float* __restrict__ wB,
                                       float* acc) {
    for (int fq = 0; fq < 18; fq++) {
        float4 h4 = *(const float4*)(hp + fq * 4);
        const float* ra = wA + fq * 300;
        const float* rb = wB + fq * 300;
#pragma unroll
        for (int k = 0; k < 4; k++) {
            float in = (k == 0) ? h4.x : (k == 1) ? h4.y : (k == 2) ? h4.z : h4.w;
#pragma unroll
            for (int j = 0; j < 15; j++) acc[j] = fmaf(in, ra[k * 75 + j], acc[j]);
#pragma unroll
            for (int j = 0; j < 15; j++) acc[15 + j] = fmaf(in, rb[k * 75 + j], acc[15 + j]);
        }
    }
#pragma unroll
    for (int f = 72; f < 75; f++) {
        float in = hp[f];
#pragma unroll
        for (int j = 0; j < 15; j++) acc[j] = fmaf(in, wA[f * 75 + j], acc[j]);
#pragma unroll
        for (int j = 0; j < 15; j++) acc[15 + j] = fmaf(in, wB[f * 75 + j], acc[15 + j]);
    }
}

// ---------------- k_base: thread-per-node x 13 pair-chunks -> baseb32[n][188] --------
__global__ __launch_bounds__(256) void k_base(const float* __restrict__ hN,
                                              const float* __restrict__ Wp,
                                              const float* __restrict__ bp,
                                              u32* __restrict__ baseb32) {
    int n = blockIdx.x * 256 + threadIdx.x;
    int p = blockIdx.y;               // 0..12, block-uniform
    if (n >= NN) return;
    const float* hp = hN + (size_t)n * 80;
    int o0 = p * 30;
    int cg = p * 2;
    int tA = cg / 5, cA = (cg % 5) * 15;
    bool full = p < 12;
    int cg1 = full ? cg + 1 : cg;
    int tB = cg1 / 5, cB = (cg1 % 5) * 15;
    float acc[30];
#pragma unroll
    for (int j = 0; j < 15; j++) acc[j] = bp[o0 + j];
#pragma unroll
    for (int j = 0; j < 15; j++) acc[15 + j] = full ? bp[o0 + 15 + j] : 0.f;
    const float* wA = Wp + (size_t)tA * 150 * 75 + cA;
    const float* wB = Wp + (size_t)tB * 150 * 75 + cB;
    gemm30(hp, wA, wB, acc);
    u32* row = baseb32 + (size_t)n * 188 + p * 15;
    if (full) {
#pragma unroll
        for (int w = 0; w < 15; w++) row[w] = pack2(acc[2 * w], acc[2 * w + 1]);
    } else {
#pragma unroll
        for (int w = 0; w < 7; w++) row[w] = pack2(acc[2 * w], acc[2 * w + 1]);
        row[7] = pack2(acc[14], 0.f);
    }
}

// ---------------- k_msg: thread-per-edge x 13 pair-chunks -> m32[row][188] ----------
__global__ __launch_bounds__(256) void k_msg(const float* __restrict__ hN,
                                             const int* __restrict__ csr,
                                             const float* __restrict__ Wp,
                                             u32* __restrict__ m32,
                                             const int* __restrict__ offs,
                                             int n0, int n1) {
    int e_begin = offs[n0], e_end = offs[n1];
    int e = e_begin + blockIdx.x * 256 + threadIdx.x;
    if (e >= e_end) return;
    int p = blockIdx.y;               // 0..12, block-uniform
    int su = csr[e];
    const float* hp = hN + (size_t)su * 80;
    int cg = p * 2;
    int tA = cg / 5, cA = (cg % 5) * 15;
    bool full = p < 12;
    int cg1 = full ? cg + 1 : cg;
    int tB = cg1 / 5, cB = (cg1 % 5) * 15;
    float acc[30];
#pragma unroll
    for (int j = 0; j < 30; j++) acc[j] = 0.f;
    const float* wA = Wp + ((size_t)tA * 150 + 75) * 75 + cA;   // src half
    const float* wB = Wp + ((size_t)tB * 150 + 75) * 75 + cB;
    gemm30(hp, wA, wB, acc);
    u32* row = m32 + (size_t)(e - e_begin) * 188 + p * 15;
    if (full) {
#pragma unroll
        for (int w = 0; w < 15; w++) row[w] = pack2(acc[2 * w], acc[2 * w + 1]);
    } else {
#pragma unroll
        for (int w = 0; w < 7; w++) row[w] = pack2(acc[2 * w], acc[2 * w + 1]);
        row[7] = pack2(acc[14], 0.f);
    }
}

// ---------------- k_agg: per-node stats over chunk-relative m32 rows ----------------
__global__ __launch_bounds__(192) void k_agg(const u32* __restrict__ m32,
                                             const int* __restrict__ offs,
                                             const u32* __restrict__ baseb32,
                                             u32* __restrict__ agg32,
                                             int n0, int n1) {
    int q = threadIdx.x;
    if (q >= 188) return;
    int e_base = offs[n0];
    int o0 = 2 * q, o1 = 2 * q + 1;
    bool has1 = o1 < 375;
    int t0 = o0 / 75, c0 = o0 % 75;
    int t1 = has1 ? (o1 / 75) : 0, c1 = has1 ? (o1 % 75) : 0;
    for (int v = n0 + blockIdx.x; v < n1; v += gridDim.x) {
        int e0 = offs[v], e1 = offs[v + 1];
        float s0 = 0.f, s1 = 0.f, sq0 = 0.f, sq1 = 0.f;
        float mn0 = 3.4e38f, mn1 = 3.4e38f, mx0 = -3.4e38f, mx1 = -3.4e38f;
        for (int e = e0; e < e1; e++) {
            u32 w = m32[(size_t)(e - e_base) * 188 + q];
            float x0 = bl2f((u16)(w & 0xffffu)), x1 = bl2f((u16)(w >> 16));
            s0 += x0; sq0 = fmaf(x0, x0, sq0); mn0 = fminf(mn0, x0); mx0 = fmaxf(mx0, x0);
            s1 += x1; sq1 = fmaf(x1, x1, sq1); mn1 = fminf(mn1, x1); mx1 = fmaxf(mx1, x1);
        }
        int deg = e1 - e0;
        u32 bw = baseb32[(size_t)v * 188 + q];
        float b0 = bl2f((u16)(bw & 0xffffu)), b1 = bl2f((u16)(bw >> 16));
        float mean0, mean1, mnf0, mnf1, mxf0, mxf1, sd0, sd1;
        if (deg > 0) {
            float im = 1.f / (float)deg;
            float mm0 = s0 * im, mm1 = s1 * im;
            float v0 = fmaxf(fmaf(-mm0, mm0, sq0 * im), 0.f);
            float v1 = fmaxf(fmaf(-mm1, mm1, sq1 * im), 0.f);
            sd0 = sqrtf(v0 + 1e-5f); sd1 = sqrtf(v1 + 1e-5f);
            mean0 = b0 + mm0; mean1 = b1 + mm1;
            mnf0 = b0 + mn0;  mnf1 = b1 + mn1;
            mxf0 = b0 + mx0;  mxf1 = b1 + mx1;
        } else {
            float sde = sqrtf(1e-5f);
            mean0 = mean1 = mnf0 = mnf1 = mxf0 = mxf1 = 0.f;
            sd0 = sd1 = sde;
        }
        u32* ap = agg32 + (size_t)(v - n0) * 768;
        ap[t0 * 152 + c0] = pack2(mean0, mnf0);
        ap[t0 * 152 + 76 + c0] = pack2(mxf0, sd0);
        if (has1) {
            ap[t1 * 152 + c1] = pack2(mean1, mnf1);
            ap[t1 * 152 + 76 + c1] = pack2(mxf1, sd1);
        }
    }
}

// ---------------- k_post: thread-per-node, one tower, c-major transposed weights ----
__global__ __launch_bounds__(256) void k_post(const float* __restrict__ hN,
                                              const int* __restrict__ offs,
                                              const u32* __restrict__ agg32,
                                              const float* __restrict__ Wq,
                                              const float* __restrict__ wqt_l,
                                              const float* __restrict__ bq,
                                              const float* __restrict__ adl_p,
                                              float* __restrict__ tmp,
                                              int n0, int n1) {
    int t = blockIdx.x;
    int n = n0 + blockIdx.y * 256 + threadIdx.x;
    if (n >= n1) return;
    float adl = adl_p[0];
    int deg = offs[n + 1] - offs[n];
    float dc = (float)(deg > 0 ? deg : 1);
    float amp = log1pf(dc) / adl;
    float inv = 1.f / amp;
    const float* wt = Wq + (size_t)t * 975 * 15;       // h-part (rows 0..74, sequential)
    const float* wq = wqt_l + (size_t)t * 13500;       // agg-part, c-major contiguous
    float acc[15];
#pragma unroll
    for (int j = 0; j < 15; j++) acc[j] = bq[t * 15 + j];
    const float4* hp4 = (const float4*)(hN + (size_t)n * 80);
#pragma unroll
    for (int fq = 0; fq < 19; fq++) {
        float4 h4 = hp4[fq];
#pragma unroll
        for (int k2 = 0; k2 < 4; k2++) {
            int kk = fq * 4 + k2;
            if (kk < 75) {
                float in = (k2 == 0) ? h4.x : (k2 == 1) ? h4.y : (k2 == 2) ? h4.z : h4.w;
                const float* wr = wt + kk * 15;
#pragma unroll
                for (int j = 0; j < 15; j++) acc[j] = fmaf(in, wr[j], acc[j]);
            }
        }
    }
    const uint4* apA = (const uint4*)(agg32 + (size_t)(n - n0) * 768 + t * 152);
    const uint4* apB = (const uint4*)(agg32 + (size_t)(n - n0) * 768 + t * 152 + 76);
    for (int cq = 0; cq < 19; cq++) {
        uint4 A = apA[cq];
        uint4 B = apB[cq];
#pragma unroll
        for (int i = 0; i < 4; i++) {
            int c = cq * 4 + i;
            if (c < 75) {
                u32 wA = (i == 0) ? A.x : (i == 1) ? A.y : (i == 2) ? A.z : A.w;
                u32 wB = (i == 0) ? B.x : (i == 1) ? B.y : (i == 2) ? B.z : B.w;
                float vs[4];
                vs[0] = bl2f((u16)(wA & 0xffffu)); vs[1] = bl2f((u16)(wA >> 16));
                vs[2] = bl2f((u16)(wB & 0xffffu)); vs[3] = bl2f((u16)(wB >> 16));
                const float* wc = wq + c * 180;    // 720 B contiguous per c
#pragma unroll
                for (int s4 = 0; s4 < 4; s4++) {
                    float a = vs[s4], aa = a * amp, ai = a * inv;
                    const float* wb = wc + s4 * 45;
#pragma unroll
                    for (int j = 0; j < 15; j++)
                        acc[j] = fmaf(a, wb[j], fmaf(aa, wb[15 + j], fmaf(ai, wb[30 + j], acc[j])));
                }
            }
        }
    }
#pragma unroll
    for (int j = 0; j < 15; j++)
        tmp[(size_t)(t * 15 + j) * NN + n] = acc[j];
}

// ---------------- k_lin2: (nodes x 5 chunks), LDS-staged Wl slice, zF out ----------
__global__ __launch_bounds__(256) void k_lin2(const float* __restrict__ tmp,
                                              const float* __restrict__ Wl,
                                              const float* __restrict__ bl,
                                              float* __restrict__ zF,
                                              float* __restrict__ bsum,
                                              float* __restrict__ bsq) {
    __shared__ __align__(16) float wl[75][16];
    __shared__ float red1[4][15], red2[4][15];
    int p = blockIdx.y;               // output chunk 0..4 (15 channels)
    for (int idx = threadIdx.x; idx < 75 * 15; idx += 256) {
        int k = idx / 15, j = idx % 15;
        wl[k][j] = Wl[k * 75 + p * 15 + j];
    }
    __syncthreads();
    int n = blockIdx.x * 256 + threadIdx.x;
    bool valid = n < NN;
    int nc = valid ? n : NN - 1;
    float acc[15];
#pragma unroll
    for (int j = 0; j < 15; j++) acc[j] = bl[p * 15 + j];
    for (int k = 0; k < 75; k++) {
        float in = tmp[(size_t)k * NN + nc];
        float4 w0 = *(const float4*)&wl[k][0];
        float4 w1 = *(const float4*)&wl[k][4];
        float4 w2 = *(const float4*)&wl[k][8];
        float4 w3 = *(const float4*)&wl[k][12];
        acc[0] = fmaf(in, w0.x, acc[0]);  acc[1] = fmaf(in, w0.y, acc[1]);
        acc[2] = fmaf(in, w0.z, acc[2]);  acc[3] = fmaf(in, w0.w, acc[3]);
        acc[4] = fmaf(in, w1.x, acc[4]);  acc[5] = fmaf(in, w1.y, acc[5]);
        acc[6] = fmaf(in, w1.z, acc[6]);  acc[7] = fmaf(in, w1.w, acc[7]);
        acc[8] = fmaf(in, w2.x, acc[8]);  acc[9] = fmaf(in, w2.y, acc[9]);
        acc[10] = fmaf(in, w2.z, acc[10]); acc[11] = fmaf(in, w2.w, acc[11]);
        acc[12] = fmaf(in, w3.x, acc[12]); acc[13] = fmaf(in, w3.y, acc[13]);
        acc[14] = fmaf(in, w3.z, acc[14]);
    }
    if (valid) {
#pragma unroll
        for (int j = 0; j < 15; j++)
            zF[(size_t)(p * 15 + j) * NN + n] = acc[j];
    }
    float s[15], ss[15];
#pragma unroll
    for (int i = 0; i < 15; i++) {
        float a = valid ? acc[i] : 0.f;
        s[i] = a; ss[i] = a * a;
    }
    for (int d = 32; d > 0; d >>= 1) {
#pragma unroll
        for (int i = 0; i < 15; i++) {
            s[i] += __shfl_down(s[i], d);
            ss[i] += __shfl_down(ss[i], d);
        }
    }
    int wave = threadIdx.x >> 6, lane = threadIdx.x & 63;
    if (lane == 0) {
#pragma unroll
        for (int i = 0; i < 15; i++) { red1[wave][i] = s[i]; red2[wave][i] = ss[i]; }
    }
    __syncthreads();
    if (threadIdx.x < 15) {
        int i = threadIdx.x;
        float a = red1[0][i] + red1[1][i] + red1[2][i] + red1[3][i];
        float b = red2[0][i] + red2[1][i] + red2[2][i] + red2[3][i];
        atomicAdd(&bsum[p * 15 + i], a);
        atomicAdd(&bsq[p * 15 + i], b);
    }
}

// ---------------- k_bn2: BN + ReLU, zF (feature-major) -> hN (node-major) ----------
__global__ __launch_bounds__(256) void k_bn2(const float* __restrict__ zF,
                                             const float* __restrict__ bsum,
                                             const float* __restrict__ bsq,
                                             const float* __restrict__ g,
                                             const float* __restrict__ b,
                                             float* __restrict__ hN) {
    int n = blockIdx.x * 256 + threadIdx.x;
    if (n >= NN) return;
    float buf[80];
    for (int c = 0; c < 75; c++) {
        float mu = bsum[c] * (1.f / NN);
        float var = bsq[c] * (1.f / NN) - mu * mu;
        float sc = g[c] * rsqrtf(var + 1e-5f);
        float v = (zF[(size_t)c * NN + n] - mu) * sc + b[c];
        buf[c] = v > 0.f ? v : 0.f;
    }
#pragma unroll
    for (int c = 75; c < 80; c++) buf[c] = 0.f;
    float4* dstp = (float4*)(hN + (size_t)n * 80);
#pragma unroll
    for (int w = 0; w < 20; w++)
        dstp[w] = make_float4(buf[4 * w], buf[4 * w + 1], buf[4 * w + 2], buf[4 * w + 3]);
}

// ---------------- MLP head ----------------
__global__ __launch_bounds__(256) void k_mlp1(const float* __restrict__ hN,
                                              const float* __restrict__ alpha,
                                              const int* __restrict__ batch,
                                              const float* __restrict__ w1,
                                              const float* __restrict__ b1,
                                              float* __restrict__ t1) {
    int n = blockIdx.x * 256 + threadIdx.x;
    if (n >= NN) return;
    float acc[50];
#pragma unroll
    for (int j = 0; j < 50; j++) acc[j] = b1[j];
    const float4* hp4 = (const float4*)(hN + (size_t)n * 80);
#pragma unroll
    for (int fq = 0; fq < 19; fq++) {
        float4 h4 = hp4[fq];
#pragma unroll
        for (int k2 = 0; k2 < 4; k2++) {
            int kk = fq * 4 + k2;
            if (kk < 75) {
                float in = (k2 == 0) ? h4.x : (k2 == 1) ? h4.y : (k2 == 2) ? h4.z : h4.w;
                const float* wr = w1 + kk * 50;
#pragma unroll
                for (int j = 0; j < 50; j++) acc[j] = fmaf(in, wr[j], acc[j]);
            }
        }
    }
    float a = alpha[batch[n]];
    const float* wr = w1 + 75 * 50;
#pragma unroll
    for (int j = 0; j < 50; j++) {
        float v = fmaf(a, wr[j], acc[j]);
        t1[(size_t)j * NN + n] = v > 0.f ? v : 0.f;
    }
}

__global__ void k_mlp2(const float* __restrict__ t1, const float* __restrict__ w2,
                       const float* __restrict__ b2, const float* __restrict__ w3,
                       const float* __restrict__ b3, const float* __restrict__ noise,
                       const float* __restrict__ x, float* __restrict__ out) {
    int n = blockIdx.x * 256 + threadIdx.x;
    if (n >= NN) return;
    float tr[50];
#pragma unroll
    for (int k = 0; k < 50; k++) tr[k] = t1[(size_t)k * NN + n];
    float y = b3[0];
#pragma unroll
    for (int k2 = 0; k2 < 25; k2++) {
        float acc = b2[k2];
#pragma unroll
        for (int k = 0; k < 50; k++) acc = fmaf(tr[k], w2[k * 25 + k2], acc);
        acc = acc > 0.f ? acc : 0.f;
        y = fmaf(acc, w3[k2], y);
    }
    float z = y + noise[n];
    float s = 1.f / (1.f + expf(-z));
    out[n] = s;
    out[NN + n] = x[2 * n];
}

extern "C" void kernel_launch(void* const* d_in, const int* in_sizes, int n_in,
                              void* d_out, int out_size, void* d_ws, size_t ws_size,
                              hipStream_t stream) {
    const float* x      = (const float*)d_in[0];
    const float* alpha  = (const float*)d_in[1];
    const int*   ei     = (const int*)d_in[2];
    const int*   batch  = (const int*)d_in[3];
    const float* noise  = (const float*)d_in[4];
    const float* adl    = (const float*)d_in[5];
    const float* pre_w  = (const float*)d_in[6];
    const float* pre_b  = (const float*)d_in[7];
    const float* W_pre  = (const float*)d_in[8];
    const float* b_pre  = (const float*)d_in[9];
    const float* W_post = (const float*)d_in[10];
    const float* b_post = (const float*)d_in[11];
    const float* W_lin  = (const float*)d_in[12];
    const float* b_lin  = (const float*)d_in[13];
    const float* bn_g   = (const float*)d_in[14];
    const float* bn_b   = (const float*)d_in[15];
    const float* mw1    = (const float*)d_in[16];
    const float* mb1    = (const float*)d_in[17];
    const float* mw2    = (const float*)d_in[18];
    const float* mb2    = (const float*)d_in[19];
    const float* mw3    = (const float*)d_in[20];
    const float* mb3    = (const float*)d_in[21];
    (void)in_sizes; (void)n_in; (void)out_size; (void)ws_size;

    char* ws = (char*)d_ws;
    size_t off = 0;
    auto alloc = [&](size_t bytes) -> char* {
        char* p = ws + off;
        off += (bytes + 255) & ~((size_t)255);
        return p;
    };
    float* hN     = (float*)alloc((size_t)NN * 80 * 4);
    float* zF     = (float*)alloc((size_t)75 * NN * 4);
    float* tmp    = (float*)alloc((size_t)75 * NN * 4);
    u32*   agg32  = (u32*)alloc((size_t)NCH * 768 * 4);
    u32*   baseb32= (u32*)alloc((size_t)NN * 188 * 4);
    u32*   m32    = (u32*)alloc((size_t)ECH * 188 * 4);
    float* wqt    = (float*)alloc((size_t)270000 * 4);       // 1.08 MB transposed W_post
    int*   cnt    = (int*)alloc((size_t)NN * 4);
    int*   offs   = (int*)alloc((size_t)(NN + 1) * 4);
    int*   fill   = (int*)alloc((size_t)NN * 4);
    int*   csr    = (int*)alloc((size_t)EE * 4);
    float* bnsum  = (float*)alloc(4 * 75 * 4);
    float* bnsq   = (float*)alloc(4 * 75 * 4);

    hipMemsetAsync(cnt, 0, (size_t)NN * 4, stream);
    hipMemsetAsync(fill, 0, (size_t)NN * 4, stream);
    hipMemsetAsync(bnsum, 0, 4 * 75 * 4, stream);
    hipMemsetAsync(bnsq, 0, 4 * 75 * 4, stream);

    const int* src = ei;
    const int* dst = ei + EE;
    int eb = (EE + 255) / 256;
    int nb = (NN + 255) / 256;
    int cb = (NCH + 255) / 256;
    int mb = (ECH + 255) / 256;

    k_count<<<eb, 256, 0, stream>>>(dst, cnt);
    k_scan<<<1, 1024, 0, stream>>>(cnt, offs);
    k_scatter<<<eb, 256, 0, stream>>>(src, dst, offs, fill, csr);
    k_pre<<<nb, 256, 0, stream>>>(x, pre_w, pre_b, hN);
    k_wqt<<<(270000 + 255) / 256, 256, 0, stream>>>(W_post, wqt);

    for (int l = 0; l < 4; l++) {
        const float* Wp  = W_pre + (size_t)l * 5 * 150 * 75;
        const float* bp  = b_pre + l * 375;
        const float* Wq  = W_post + (size_t)l * 5 * 975 * 15;
        const float* wqtl= wqt + (size_t)l * 67500;
        const float* bq  = b_post + l * 75;
        const float* Wl  = W_lin + l * 75 * 75;
        const float* blp = b_lin + l * 75;
        k_base<<<dim3(nb, 13), 256, 0, stream>>>(hN, Wp, bp, baseb32);
        for (int ch = 0; ch < 2; ch++) {
            int n0 = ch * NCH, n1 = n0 + NCH;
            k_msg<<<dim3(mb, 13), 256, 0, stream>>>(hN, csr, Wp, m32, offs, n0, n1);
            k_agg<<<2048, 192, 0, stream>>>(m32, offs, baseb32, agg32, n0, n1);
            k_post<<<dim3(5, cb), 256, 0, stream>>>(hN, offs, agg32, Wq, wqtl, bq, adl, tmp, n0, n1);
        }
        k_lin2<<<dim3(nb, 5), 256, 0, stream>>>(tmp, Wl, blp, zF, bnsum + l * 75, bnsq + l * 75);
        k_bn2<<<nb, 256, 0, stream>>>(zF, bnsum + l * 75, bnsq + l * 75,
                                      bn_g + l * 75, bn_b + l * 75, hN);
    }

    float* t1 = tmp;
    k_mlp1<<<nb, 256, 0, stream>>>(hN, alpha, batch, mw1, mb1, t1);
    k_mlp2<<<nb, 256, 0, stream>>>(t1, mw2, mb2, mw3, mb3, noise, x, (float*)d_out);
}